// Round 3
// baseline (2837.949 us; speedup 1.0000x reference)
//
#include <hip/hip_runtime.h>
#include <math.h>

// Problem constants (fixed by the reference)
static constexpr int Bc    = 4;
static constexpr int Tc    = 2048;
static constexpr int HIDc  = 1024;
static constexpr int NHc   = 8;
static constexpr int HDc   = 128;   // HID/NH
static constexpr int Mrows = Bc * Tc;          // 8192
static constexpr int INTERc= 2816;

static __device__ __forceinline__ float sigm(float x) { return 1.0f / (1.0f + expf(-x)); }
static __device__ __forceinline__ float silu(float x) { return x * sigm(x); }
static __device__ __forceinline__ float elu1(float x) { return x > 0.0f ? x + 1.0f : expf(x); }

union F4 { float4 v; float a[4]; };
union S8 { short s[8]; int4 v; };

typedef __attribute__((ext_vector_type(8))) short bf16x8;
typedef __attribute__((ext_vector_type(4))) float f32x4;

// fp32 -> (bf16 hi, bf16 lo) RNE split: x ~= hi + lo, |err| <~ 2^-17 |x|
static __device__ __forceinline__ void cvt2(float x, short& hi, short& lo)
{
    unsigned u = __float_as_uint(x);
    unsigned r = u + 0x7FFFu + ((u >> 16) & 1u);
    hi = (short)(r >> 16);
    float hf = __uint_as_float(r & 0xFFFF0000u);
    float res = x - hf;
    unsigned u2 = __float_as_uint(res);
    unsigned r2 = u2 + 0x7FFFu + ((u2 >> 16) & 1u);
    lo = (short)(r2 >> 16);
}

// ---------------------------------------------------------------------------
// Weight split: fp32 [n] -> bf16 hi[n], lo[n]   (only used when ws has room)
// ---------------------------------------------------------------------------
__global__ __launch_bounds__(256) void wsplit_k(const float* __restrict__ src,
                                                short* __restrict__ hi,
                                                short* __restrict__ lo, int n4)
{
    const int i = blockIdx.x * 256 + threadIdx.x;
    if (i >= n4) return;
    F4 f; f.v = ((const float4*)src)[i];
    union { short s[4]; int2 v; } H, L;
    #pragma unroll
    for (int u = 0; u < 4; u++) cvt2(f.a[u], H.s[u], L.s[u]);
    *(int2*)&hi[(size_t)i * 4] = H.v;
    *(int2*)&lo[(size_t)i * 4] = L.v;
}

// ---------------------------------------------------------------------------
// RMSNorm: one block per row (1024 cols), 256 threads, float4 per thread
// ---------------------------------------------------------------------------
__global__ __launch_bounds__(256) void rmsnorm_k(const float* __restrict__ x,
                                                 const float* __restrict__ w,
                                                 float* __restrict__ out)
{
    const int row = blockIdx.x;
    const int tid = threadIdx.x;
    F4 v; v.v = ((const float4*)(x + (size_t)row * HIDc))[tid];
    float ss = v.a[0]*v.a[0] + v.a[1]*v.a[1] + v.a[2]*v.a[2] + v.a[3]*v.a[3];
    #pragma unroll
    for (int off = 32; off > 0; off >>= 1) ss += __shfl_xor(ss, off);
    __shared__ float sred[4];
    if ((tid & 63) == 0) sred[tid >> 6] = ss;
    __syncthreads();
    const float tot = sred[0] + sred[1] + sred[2] + sred[3];
    const float scale = rsqrtf(tot * (1.0f / (float)HIDc) + 1e-6f);
    F4 wv; wv.v = ((const float4*)w)[tid];
    F4 o;
    #pragma unroll
    for (int u = 0; u < 4; u++) o.a[u] = v.a[u] * scale * wv.a[u];
    ((float4*)(out + (size_t)row * HIDc))[tid] = o.v;
}

// ---------------------------------------------------------------------------
// Depthwise causal conv (KS=4) + bias + SiLU.  One block per row (b,t).
// ---------------------------------------------------------------------------
__global__ __launch_bounds__(256) void conv_k(const float* __restrict__ h,
                                              const float* __restrict__ cw,
                                              const float* __restrict__ cb,
                                              float* __restrict__ c)
{
    const int row = blockIdx.x;           // b*T + t
    const int t   = row & (Tc - 1);       // T = 2048 (pow2)
    const int ch4 = threadIdx.x * 4;
    const float* wp = cw + (size_t)ch4 * 4;
    F4 bias; bias.v = *(const float4*)(cb + ch4);
    F4 acc;
    #pragma unroll
    for (int u = 0; u < 4; u++) acc.a[u] = bias.a[u];
    #pragma unroll
    for (int j = 0; j < 4; j++) {
        const int tt = t - 3 + j;
        if (tt >= 0) {
            F4 xv; xv.v = *(const float4*)(h + ((size_t)row + j - 3) * HIDc + ch4);
            #pragma unroll
            for (int u = 0; u < 4; u++) acc.a[u] += xv.a[u] * wp[u * 4 + j];
        }
    }
    F4 o;
    #pragma unroll
    for (int u = 0; u < 4; u++) o.a[u] = silu(acc.a[u]);
    *(float4*)(c + (size_t)row * HIDc + ch4) = o.v;
}

// ---------------------------------------------------------------------------
// Linear-attention decay scan.  One block (1 wave) per (b, head); lane owns
// 2 of the 128 head dims.  q,k,v are separate [B*T, HID] planes.
// ---------------------------------------------------------------------------
__global__ __launch_bounds__(64) void attn_scan_k(const float* __restrict__ q,
                                                  const float* __restrict__ k,
                                                  const float* __restrict__ v,
                                                  const float* __restrict__ decay_param,
                                                  float* __restrict__ o)
{
    const int bh = blockIdx.x;
    const int b  = bh >> 3;
    const int hh = bh & 7;
    const int lane = threadIdx.x;
    const float dec = sigm(decay_param[hh]);
    const size_t off = (size_t)b * Tc * HIDc + hh * HDc + lane * 2;
    const float* qb = q + off;
    const float* kb = k + off;
    const float* vb = v + off;
    float* ob = o + off;
    float skv0 = 0.f, skv1 = 0.f, sks0 = 0.f, sks1 = 0.f;
    for (int t = 0; t < Tc; t++) {
        const size_t p = (size_t)t * HIDc;
        float2 qv = *(const float2*)(qb + p);
        float2 kv = *(const float2*)(kb + p);
        float2 vv = *(const float2*)(vb + p);
        const float qx = elu1(qv.x), qy = elu1(qv.y);
        const float kx = elu1(kv.x), ky = elu1(kv.y);
        skv0 = dec * skv0 + kx * vv.x;
        skv1 = dec * skv1 + ky * vv.y;
        sks0 = dec * sks0 + kx;
        sks1 = dec * sks1 + ky;
        float part = qx * sks0 + qy * sks1;
        #pragma unroll
        for (int o2 = 32; o2 > 0; o2 >>= 1) part += __shfl_xor(part, o2);
        const float inv = 1.0f / fmaxf(part, 1e-6f);
        float2 outv;
        outv.x = qx * skv0 * inv;
        outv.y = qy * skv1 * inv;
        *(float2*)(ob + p) = outv;
    }
}

// ---------------------------------------------------------------------------
// bf16x3 MFMA GEMM:  C[M,N] = A[M,K] @ W[N,K]^T  (+ fused epilogues)
// A fp32 (split on the fly).  W: PRE=1 -> pre-split bf16 hi/lo; PRE=0 -> fp32
// split on the fly.  128x128 tile, BK=32, 4 waves (2x2), 4x4 16x16x32 frags.
// MODE 0: C = acc
// MODE 1: C = silu(acc)
// MODE 2: C = C * acc                           (read-modify-write)
// MODE 3: g = sigm(acc + bias[n]); C = g*E0 + (1-g)*E1
// MODE 4: g = sigm(acc);           C = E0 + g*E1 + (1-g)*E2   (A split at kSplit -> A2)
// MODE 6: C = C + acc                           (read-modify-write add)
// ---------------------------------------------------------------------------
template<int MODE, int PRE>
__global__ __launch_bounds__(256) void gemm_m3_k(
    const float* __restrict__ A, const float* __restrict__ A2, int lda,
    const short* __restrict__ Wh, const short* __restrict__ Wl,
    const float* __restrict__ Wf,
    float* __restrict__ C, int ldc,
    int K, int kSplit,
    const float* __restrict__ bias,
    const float* __restrict__ E0, int ldE0,
    const float* __restrict__ E1, int ldE1,
    const float* __restrict__ E2, int ldE2)
{
    // k-chunk-major LDS: [k-chunk of 8][row 0..127][8 bf16]
    __shared__ __align__(16) short Ah[4][128][8];
    __shared__ __align__(16) short Al[4][128][8];
    __shared__ __align__(16) short Bh[4][128][8];
    __shared__ __align__(16) short Bl[4][128][8];

    const int tid  = threadIdx.x;
    const int lane = tid & 63;
    const int w    = tid >> 6;
    const int wr   = w >> 1, wc = w & 1;      // wave 2x2 grid, 64x64 out each
    const int lr   = lane & 15, lk = lane >> 4;
    const int m0 = blockIdx.y * 128, n0 = blockIdx.x * 128;

    const int arow = tid & 127;
    const int ksel = tid >> 7;                 // 0 or 1
    const int cA   = ksel * 2;                 // chunk base (k/8)

    f32x4 acc[4][4];
    #pragma unroll
    for (int i = 0; i < 4; i++)
        #pragma unroll
        for (int j = 0; j < 4; j++)
            acc[i][j] = (f32x4){0.f, 0.f, 0.f, 0.f};

    for (int k0 = 0; k0 < K; k0 += 32) {
        const float* Asrc = A; int kb = k0;
        if constexpr (MODE == 4) {
            if (k0 >= kSplit) { Asrc = A2; kb = k0 - kSplit; }
        }
        // ---- global loads ----
        const float* ap = &Asrc[(size_t)(m0 + arow) * lda + kb + ksel * 16];
        F4 f[4];
        #pragma unroll
        for (int q = 0; q < 4; q++) f[q].v = *(const float4*)(ap + q * 4);

        int4 wh0, wh1, wl0, wl1;
        if constexpr (PRE) {
            const size_t woff = (size_t)(n0 + arow) * K + k0 + ksel * 16;
            wh0 = *(const int4*)(Wh + woff);
            wh1 = *(const int4*)(Wh + woff + 8);
            wl0 = *(const int4*)(Wl + woff);
            wl1 = *(const int4*)(Wl + woff + 8);
        } else {
            const float* wpf = &Wf[(size_t)(n0 + arow) * K + k0 + ksel * 16];
            F4 g[4];
            #pragma unroll
            for (int q = 0; q < 4; q++) g[q].v = *(const float4*)(wpf + q * 4);
            S8 H0, H1, L0, L1;
            #pragma unroll
            for (int e = 0; e < 8; e++) {
                cvt2(g[e >> 2].a[e & 3],       H0.s[e], L0.s[e]);
                cvt2(g[2 + (e >> 2)].a[e & 3], H1.s[e], L1.s[e]);
            }
            wh0 = H0.v; wh1 = H1.v; wl0 = L0.v; wl1 = L1.v;
        }
        // ---- split A fp32 -> hi/lo bf16 ----
        S8 h0, h1, l0, l1;
        #pragma unroll
        for (int e = 0; e < 8; e++) {
            cvt2(f[e >> 2].a[e & 3],       h0.s[e], l0.s[e]);
            cvt2(f[2 + (e >> 2)].a[e & 3], h1.s[e], l1.s[e]);
        }
        __syncthreads();   // previous iteration's LDS reads done
        *(int4*)&Ah[cA][arow][0]     = h0.v;
        *(int4*)&Ah[cA + 1][arow][0] = h1.v;
        *(int4*)&Al[cA][arow][0]     = l0.v;
        *(int4*)&Al[cA + 1][arow][0] = l1.v;
        *(int4*)&Bh[cA][arow][0]     = wh0;
        *(int4*)&Bh[cA + 1][arow][0] = wh1;
        *(int4*)&Bl[cA][arow][0]     = wl0;
        *(int4*)&Bl[cA + 1][arow][0] = wl1;
        __syncthreads();
        // ---- fragments + 3-term MFMA ----
        bf16x8 av[4], au[4], bv[4], bu[4];
        #pragma unroll
        for (int fi = 0; fi < 4; fi++) {
            av[fi] = *(const bf16x8*)&Ah[lk][wr * 64 + fi * 16 + lr][0];
            au[fi] = *(const bf16x8*)&Al[lk][wr * 64 + fi * 16 + lr][0];
            bv[fi] = *(const bf16x8*)&Bh[lk][wc * 64 + fi * 16 + lr][0];
            bu[fi] = *(const bf16x8*)&Bl[lk][wc * 64 + fi * 16 + lr][0];
        }
        #pragma unroll
        for (int i = 0; i < 4; i++)
            #pragma unroll
            for (int j = 0; j < 4; j++) {
                acc[i][j] = __builtin_amdgcn_mfma_f32_16x16x32_bf16(av[i], bv[j], acc[i][j], 0, 0, 0);
                acc[i][j] = __builtin_amdgcn_mfma_f32_16x16x32_bf16(av[i], bu[j], acc[i][j], 0, 0, 0);
                acc[i][j] = __builtin_amdgcn_mfma_f32_16x16x32_bf16(au[i], bv[j], acc[i][j], 0, 0, 0);
            }
    }

    // ---- epilogue: C/D layout col=lane&15, row=(lane>>4)*4+reg ----
    #pragma unroll
    for (int i = 0; i < 4; i++) {
        #pragma unroll
        for (int j = 0; j < 4; j++) {
            #pragma unroll
            for (int v = 0; v < 4; v++) {
                const size_t r = (size_t)(m0 + wr * 64 + i * 16 + lk * 4 + v);
                const int c = n0 + wc * 64 + j * 16 + lr;
                float val = acc[i][j][v];
                if constexpr (MODE == 1) {
                    val = silu(val);
                } else if constexpr (MODE == 2) {
                    val = C[r * ldc + c] * val;
                } else if constexpr (MODE == 3) {
                    const float g = sigm(val + bias[c]);
                    val = g * E0[r * ldE0 + c] + (1.0f - g) * E1[r * ldE1 + c];
                } else if constexpr (MODE == 4) {
                    const float g = sigm(val);
                    val = E0[r * ldE0 + c] + g * E1[r * ldE1 + c] + (1.0f - g) * E2[r * ldE2 + c];
                } else if constexpr (MODE == 6) {
                    val = C[r * ldc + c] + val;
                }
                C[r * ldc + c] = val;
            }
        }
    }
}

// host-side dispatch helper (branches on pre-split availability)
template<int MODE>
static inline void launch_gemm(bool pre, dim3 grid, hipStream_t stream,
    const float* A, const float* A2, int lda,
    const short* Wh, const short* Wl, const float* Wf,
    float* C, int ldc, int K, int kSplit,
    const float* bias,
    const float* E0, int ldE0, const float* E1, int ldE1, const float* E2, int ldE2)
{
    if (pre)
        gemm_m3_k<MODE, 1><<<grid, dim3(256), 0, stream>>>(A, A2, lda, Wh, Wl, Wf, C, ldc,
                                                           K, kSplit, bias, E0, ldE0, E1, ldE1, E2, ldE2);
    else
        gemm_m3_k<MODE, 0><<<grid, dim3(256), 0, stream>>>(A, A2, lda, Wh, Wl, Wf, C, ldc,
                                                           K, kSplit, bias, E0, ldE0, E1, ldE1, E2, ldE2);
}

// ---------------------------------------------------------------------------
extern "C" void kernel_launch(void* const* d_in, const int* in_sizes, int n_in,
                              void* d_out, int out_size, void* d_ws, size_t ws_size,
                              hipStream_t stream)
{
    const float* x           = (const float*)d_in[0];
    const float* qkv_w       = (const float*)d_in[1];
    const float* out_proj_w  = (const float*)d_in[2];
    const float* out_gate_w  = (const float*)d_in[3];
    const float* out_gate_b  = (const float*)d_in[4];
    const float* decay_param = (const float*)d_in[5];
    const float* conv_w      = (const float*)d_in[6];
    const float* conv_b      = (const float*)d_in[7];
    const float* pw_w        = (const float*)d_in[8];
    const float* gate_w      = (const float*)d_in[9];
    const float* w1          = (const float*)d_in[10];
    const float* w2          = (const float*)d_in[11];
    const float* w3          = (const float*)d_in[12];
    const float* norm1_w     = (const float*)d_in[13];
    const float* norm2_w     = (const float*)d_in[14];
    float* OUT = (float*)d_out;

    // ---- workspace layout: 4 fp32 planes of 32MB; d_out is the 5th plane ----
    float* ws = (float*)d_ws;
    const size_t S8 = (size_t)Mrows * HIDc;   // 8,388,608 floats = 32MB
    float* P0 = ws;
    float* P1 = P0 + S8;
    float* P2 = P1 + S8;
    float* P3 = P2 + S8;

    // optional pre-split bf16 weight region after the 4 planes
    constexpr size_t SZ_QKV  = (size_t)3 * HIDc * HIDc;   // 3,145,728
    constexpr size_t SZ_SQ   = (size_t)HIDc * HIDc;       // 1,048,576
    constexpr size_t SZ_GATE = (size_t)2 * HIDc * HIDc;   // 2,097,152
    constexpr size_t SZ_W1   = (size_t)INTERc * HIDc;     // 2,883,584
    constexpr size_t W_ELEMS = SZ_QKV + 3 * SZ_SQ + SZ_GATE + 3 * SZ_W1;  // 17,039,360
    const size_t base_bytes = 4 * S8 * sizeof(float);             // 134,217,728
    const size_t pre_bytes  = base_bytes + 2 * W_ELEMS * sizeof(short); // ~202.4MB
    const bool pre = (ws_size >= pre_bytes);

    short* wb = (short*)(ws + 4 * S8);
    short* qkv_h = wb;                 short* qkv_l = qkv_h + SZ_QKV;
    short* pw_h  = qkv_l + SZ_QKV;     short* pw_l  = pw_h  + SZ_SQ;
    short* og_h  = pw_l  + SZ_SQ;      short* og_l  = og_h  + SZ_SQ;
    short* op_h  = og_l  + SZ_SQ;      short* op_l  = op_h  + SZ_SQ;
    short* ga_h  = op_l  + SZ_SQ;      short* ga_l  = ga_h  + SZ_GATE;
    short* w1_h  = ga_l  + SZ_GATE;    short* w1_l  = w1_h  + SZ_W1;
    short* w2_h  = w1_l  + SZ_W1;      short* w2_l  = w2_h  + SZ_W1;
    short* w3_h  = w2_l  + SZ_W1;      short* w3_l  = w3_h  + SZ_W1;

    const dim3 blk(256);
    const dim3 g8(8, Mrows / 128);    // N=1024
    const dim3 g22(22, Mrows / 128);  // N=2816

    if (pre) {
        wsplit_k<<<(int)(SZ_QKV / 4 / 256), blk, 0, stream>>>(qkv_w, qkv_h, qkv_l, (int)(SZ_QKV / 4));
        wsplit_k<<<(int)(SZ_SQ  / 4 / 256), blk, 0, stream>>>(pw_w,  pw_h,  pw_l,  (int)(SZ_SQ  / 4));
        wsplit_k<<<(int)(SZ_SQ  / 4 / 256), blk, 0, stream>>>(out_gate_w, og_h, og_l, (int)(SZ_SQ / 4));
        wsplit_k<<<(int)(SZ_SQ  / 4 / 256), blk, 0, stream>>>(out_proj_w, op_h, op_l, (int)(SZ_SQ / 4));
        wsplit_k<<<(int)(SZ_GATE/ 4 / 256), blk, 0, stream>>>(gate_w, ga_h, ga_l, (int)(SZ_GATE / 4));
        wsplit_k<<<(int)(SZ_W1  / 4 / 256), blk, 0, stream>>>(w1, w1_h, w1_l, (int)(SZ_W1 / 4));
        wsplit_k<<<(int)(SZ_W1  / 4 / 256), blk, 0, stream>>>(w2, w2_h, w2_l, (int)(SZ_W1 / 4));
        wsplit_k<<<(int)(SZ_W1  / 4 / 256), blk, 0, stream>>>(w3, w3_h, w3_l, (int)(SZ_W1 / 4));
    }

    // 1. h = rmsnorm(x, norm1_w) -> P0
    rmsnorm_k<<<Mrows, blk, 0, stream>>>(x, norm1_w, P0);
    // 2. conv + bias + silu  (P0 -> P1)
    conv_k<<<Mrows, blk, 0, stream>>>(P0, conv_w, conv_b, P1);
    // 3. local = conv_silu @ pw_w^T  (P1 -> P2)
    launch_gemm<0>(pre, g8, stream, P1, nullptr, HIDc, pw_h, pw_l, pw_w, P2, HIDc,
                   HIDc, 0, nullptr, nullptr, 0, nullptr, 0, nullptr, 0);
    // 4. q,k,v = h @ qkv_w^T  (P0 -> P1, P3, OUT)
    launch_gemm<0>(pre, g8, stream, P0, nullptr, HIDc, qkv_h, qkv_l, qkv_w, P1, HIDc,
                   HIDc, 0, nullptr, nullptr, 0, nullptr, 0, nullptr, 0);
    launch_gemm<0>(pre, g8, stream, P0, nullptr, HIDc,
                   qkv_h + SZ_SQ, qkv_l + SZ_SQ, qkv_w + SZ_SQ, P3, HIDc,
                   HIDc, 0, nullptr, nullptr, 0, nullptr, 0, nullptr, 0);
    launch_gemm<0>(pre, g8, stream, P0, nullptr, HIDc,
                   qkv_h + 2 * SZ_SQ, qkv_l + 2 * SZ_SQ, qkv_w + 2 * SZ_SQ, OUT, HIDc,
                   HIDc, 0, nullptr, nullptr, 0, nullptr, 0, nullptr, 0);
    // 5. linear attention scan  (q=P1,k=P3,v=OUT -> o=P0)
    attn_scan_k<<<Bc * NHc, dim3(64), 0, stream>>>(P1, P3, OUT, decay_param, P0);
    // 6. out-gate: g = sigm(o@Wg^T + b); o2 = g*o + (1-g)*v   (-> P1)
    launch_gemm<3>(pre, g8, stream, P0, nullptr, HIDc, og_h, og_l, out_gate_w, P1, HIDc,
                   HIDc, 0, out_gate_b, P0, HIDc, OUT, HIDc, nullptr, 0);
    // 7. attn = o2 @ out_proj_w^T  (P1 -> P3)
    launch_gemm<0>(pre, g8, stream, P1, nullptr, HIDc, op_h, op_l, out_proj_w, P3, HIDc,
                   HIDc, 0, nullptr, nullptr, 0, nullptr, 0, nullptr, 0);
    // 8. gmix = sigm([local,attn]@gate_w^T); x1 = x + g*local + (1-g)*attn (-> OUT)
    launch_gemm<4>(pre, g8, stream, P2, P3, HIDc, ga_h, ga_l, gate_w, OUT, HIDc,
                   2 * HIDc, HIDc, nullptr, x, HIDc, P2, HIDc, P3, HIDc);
    // 9. h2 = rmsnorm(x1, norm2_w)  (OUT -> P0)
    rmsnorm_k<<<Mrows, blk, 0, stream>>>(OUT, norm2_w, P0);
    // 10. t1 = silu(h2 @ w1^T)  (-> P1 span, ld 2816; fits in P1..P3 = 96MB)
    launch_gemm<1>(pre, g22, stream, P0, nullptr, HIDc, w1_h, w1_l, w1, P1, INTERc,
                   HIDc, 0, nullptr, nullptr, 0, nullptr, 0, nullptr, 0);
    // 11. u = t1 * (h2 @ w2^T)  (RMW P1 span)
    launch_gemm<2>(pre, g22, stream, P0, nullptr, HIDc, w2_h, w2_l, w2, P1, INTERc,
                   HIDc, 0, nullptr, nullptr, 0, nullptr, 0, nullptr, 0);
    // 12. OUT = x1 + u @ w3^T  (RMW add into d_out)
    launch_gemm<6>(pre, g8, stream, P1, nullptr, INTERc, w3_h, w3_l, w3, OUT, HIDc,
                   INTERc, 0, nullptr, nullptr, 0, nullptr, 0, nullptr, 0);
}

// Round 4
// 1796.222 us; speedup vs baseline: 1.5800x; 1.5800x over previous
//
#include <hip/hip_runtime.h>
#include <math.h>

// Problem constants (fixed by the reference)
static constexpr int Bc    = 4;
static constexpr int Tc    = 2048;
static constexpr int HIDc  = 1024;
static constexpr int NHc   = 8;
static constexpr int HDc   = 128;   // HID/NH
static constexpr int Mrows = Bc * Tc;          // 8192
static constexpr int INTERc= 2816;
static constexpr int CH    = 64;    // scan chunk length
static constexpr int NC    = Tc / CH;   // 32 chunks

static __device__ __forceinline__ float sigm(float x) { return 1.0f / (1.0f + expf(-x)); }
static __device__ __forceinline__ float silu(float x) { return x * sigm(x); }
static __device__ __forceinline__ float elu1(float x) { return x > 0.0f ? x + 1.0f : expf(x); }

union F4 { float4 v; float a[4]; };
union S8 { short s[8]; int4 v; };

typedef __attribute__((ext_vector_type(8))) short bf16x8;
typedef __attribute__((ext_vector_type(4))) float f32x4;

// fp32 -> (bf16 hi, bf16 lo) RNE split: x ~= hi + lo, |err| <~ 2^-17 |x|
static __device__ __forceinline__ void cvt2(float x, short& hi, short& lo)
{
    unsigned u = __float_as_uint(x);
    unsigned r = u + 0x7FFFu + ((u >> 16) & 1u);
    hi = (short)(r >> 16);
    float hf = __uint_as_float(r & 0xFFFF0000u);
    float res = x - hf;
    unsigned u2 = __float_as_uint(res);
    unsigned r2 = u2 + 0x7FFFu + ((u2 >> 16) & 1u);
    lo = (short)(r2 >> 16);
}

// ---------------------------------------------------------------------------
// Weight split: fp32 [n] -> bf16 hi[n], lo[n]   (only used when ws has room)
// ---------------------------------------------------------------------------
__global__ __launch_bounds__(256) void wsplit_k(const float* __restrict__ src,
                                                short* __restrict__ hi,
                                                short* __restrict__ lo, int n4)
{
    const int i = blockIdx.x * 256 + threadIdx.x;
    if (i >= n4) return;
    F4 f; f.v = ((const float4*)src)[i];
    union { short s[4]; int2 v; } H, L;
    #pragma unroll
    for (int u = 0; u < 4; u++) cvt2(f.a[u], H.s[u], L.s[u]);
    *(int2*)&hi[(size_t)i * 4] = H.v;
    *(int2*)&lo[(size_t)i * 4] = L.v;
}

// ---------------------------------------------------------------------------
// RMSNorm: one block per row (1024 cols), 256 threads, float4 per thread
// ---------------------------------------------------------------------------
__global__ __launch_bounds__(256) void rmsnorm_k(const float* __restrict__ x,
                                                 const float* __restrict__ w,
                                                 float* __restrict__ out)
{
    const int row = blockIdx.x;
    const int tid = threadIdx.x;
    F4 v; v.v = ((const float4*)(x + (size_t)row * HIDc))[tid];
    float ss = v.a[0]*v.a[0] + v.a[1]*v.a[1] + v.a[2]*v.a[2] + v.a[3]*v.a[3];
    #pragma unroll
    for (int off = 32; off > 0; off >>= 1) ss += __shfl_xor(ss, off);
    __shared__ float sred[4];
    if ((tid & 63) == 0) sred[tid >> 6] = ss;
    __syncthreads();
    const float tot = sred[0] + sred[1] + sred[2] + sred[3];
    const float scale = rsqrtf(tot * (1.0f / (float)HIDc) + 1e-6f);
    F4 wv; wv.v = ((const float4*)w)[tid];
    F4 o;
    #pragma unroll
    for (int u = 0; u < 4; u++) o.a[u] = v.a[u] * scale * wv.a[u];
    ((float4*)(out + (size_t)row * HIDc))[tid] = o.v;
}

// ---------------------------------------------------------------------------
// Depthwise causal conv (KS=4) + bias + SiLU.  One block per row (b,t).
// ---------------------------------------------------------------------------
__global__ __launch_bounds__(256) void conv_k(const float* __restrict__ h,
                                              const float* __restrict__ cw,
                                              const float* __restrict__ cb,
                                              float* __restrict__ c)
{
    const int row = blockIdx.x;           // b*T + t
    const int t   = row & (Tc - 1);       // T = 2048 (pow2)
    const int ch4 = threadIdx.x * 4;
    const float* wp = cw + (size_t)ch4 * 4;
    F4 bias; bias.v = *(const float4*)(cb + ch4);
    F4 acc;
    #pragma unroll
    for (int u = 0; u < 4; u++) acc.a[u] = bias.a[u];
    #pragma unroll
    for (int j = 0; j < 4; j++) {
        const int tt = t - 3 + j;
        if (tt >= 0) {
            F4 xv; xv.v = *(const float4*)(h + ((size_t)row + j - 3) * HIDc + ch4);
            #pragma unroll
            for (int u = 0; u < 4; u++) acc.a[u] += xv.a[u] * wp[u * 4 + j];
        }
    }
    F4 o;
    #pragma unroll
    for (int u = 0; u < 4; u++) o.a[u] = silu(acc.a[u]);
    *(float4*)(c + (size_t)row * HIDc + ch4) = o.v;
}

// ---------------------------------------------------------------------------
// Chunked linear-attention scan, step 1: per-chunk LOCAL scans.
// Grid: B*NH*NC blocks, 64 lanes, 2 dims/lane, 64 timesteps serial.
// Reads k (kp) and v (vp); writes local skv over kp IN-PLACE, local sks to sksp.
// Chunk-end states are simply the t = chunk_end rows (no extra storage).
// ---------------------------------------------------------------------------
__global__ __launch_bounds__(64) void scan1_k(float* __restrict__ kp,
                                              const float* __restrict__ vp,
                                              float* __restrict__ sksp,
                                              const float* __restrict__ decay_param)
{
    const int bid = blockIdx.x;
    const int c   = bid & (NC - 1);
    const int bh  = bid >> 5;              // NC=32
    const int b   = bh >> 3, hh = bh & 7;
    const int lane = threadIdx.x;
    const float dec = sigm(decay_param[hh]);
    const size_t base = (size_t)b * Tc * HIDc + (size_t)(c * CH) * HIDc + hh * HDc + lane * 2;
    float skv0 = 0.f, skv1 = 0.f, sks0 = 0.f, sks1 = 0.f;
    for (int t = 0; t < CH; t++) {
        const size_t p = base + (size_t)t * HIDc;
        float2 kv = *(const float2*)(kp + p);
        float2 vv = *(const float2*)(vp + p);
        const float kx = elu1(kv.x), ky = elu1(kv.y);
        skv0 = dec * skv0 + kx * vv.x;
        skv1 = dec * skv1 + ky * vv.y;
        sks0 = dec * sks0 + kx;
        sks1 = dec * sks1 + ky;
        float2 wkv; wkv.x = skv0; wkv.y = skv1;
        float2 wks; wks.x = sks0; wks.y = sks1;
        *(float2*)(kp + p)   = wkv;
        *(float2*)(sksp + p) = wks;
    }
}

// ---------------------------------------------------------------------------
// Chunked scan, step 2: carry combine + output.
// Each block (b,h,chunk c): carry = sum_{j<c} d^{CH*(c-1-j)} * end[j], where
// end[j] = local value at t = j*CH+CH-1 (read from skvp/sksp).  Then for each
// t in chunk: S = local + d^(tl+1)*carry; den = wave-reduce(q . Sks);
// o = q * Skv / den, written IN-PLACE over q.
// ---------------------------------------------------------------------------
__global__ __launch_bounds__(64) void scan2_k(float* __restrict__ qp,
                                              const float* __restrict__ skvp,
                                              const float* __restrict__ sksp,
                                              const float* __restrict__ decay_param)
{
    const int bid = blockIdx.x;
    const int c   = bid & (NC - 1);
    const int bh  = bid >> 5;
    const int b   = bh >> 3, hh = bh & 7;
    const int lane = threadIdx.x;
    const float dec = sigm(decay_param[hh]);
    float dCH = dec;
    #pragma unroll
    for (int i = 0; i < 6; i++) dCH *= dCH;      // dec^64
    const size_t rowbase = (size_t)b * Tc * HIDc + hh * HDc + lane * 2;

    float ckv0 = 0.f, ckv1 = 0.f, cks0 = 0.f, cks1 = 0.f;
    for (int j = 0; j < c; j++) {
        const size_t p = rowbase + (size_t)(j * CH + CH - 1) * HIDc;
        float2 ekv = *(const float2*)(skvp + p);
        float2 eks = *(const float2*)(sksp + p);
        ckv0 = ckv0 * dCH + ekv.x;
        ckv1 = ckv1 * dCH + ekv.y;
        cks0 = cks0 * dCH + eks.x;
        cks1 = cks1 * dCH + eks.y;
    }

    const size_t cbase = rowbase + (size_t)(c * CH) * HIDc;
    float pw = dec;
    for (int t = 0; t < CH; t++) {
        const size_t p = cbase + (size_t)t * HIDc;
        float2 qv  = *(const float2*)(qp + p);
        float2 lkv = *(const float2*)(skvp + p);
        float2 lks = *(const float2*)(sksp + p);
        const float qx = elu1(qv.x), qy = elu1(qv.y);
        const float skv0 = lkv.x + pw * ckv0, skv1 = lkv.y + pw * ckv1;
        const float sks0 = lks.x + pw * cks0, sks1 = lks.y + pw * cks1;
        float part = qx * sks0 + qy * sks1;
        #pragma unroll
        for (int off = 32; off > 0; off >>= 1) part += __shfl_xor(part, off);
        const float inv = 1.0f / fmaxf(part, 1e-6f);
        float2 outv;
        outv.x = qx * skv0 * inv;
        outv.y = qy * skv1 * inv;
        *(float2*)(qp + p) = outv;
        pw *= dec;
    }
}

// ---------------------------------------------------------------------------
// bf16x3 MFMA GEMM:  C[M,N] = A[M,K] @ W[N,K]^T  (+ fused epilogues)
// A fp32 (split on the fly).  W: PRE=1 -> pre-split bf16 hi/lo; PRE=0 -> fp32
// split on the fly.  128x128 tile, BK=32, 4 waves (2x2), 4x4 16x16x32 frags.
// MODE 0: C = acc
// MODE 1: C = silu(acc)
// MODE 2: C = C * acc                           (read-modify-write)
// MODE 3: g = sigm(acc + bias[n]); C = g*E0 + (1-g)*E1
// MODE 4: g = sigm(acc);           C = E0 + g*E1 + (1-g)*E2   (A split at kSplit -> A2)
// MODE 6: C = C + acc                           (read-modify-write add)
// ---------------------------------------------------------------------------
template<int MODE, int PRE>
__global__ __launch_bounds__(256) void gemm_m3_k(
    const float* __restrict__ A, const float* __restrict__ A2, int lda,
    const short* __restrict__ Wh, const short* __restrict__ Wl,
    const float* __restrict__ Wf,
    float* __restrict__ C, int ldc,
    int K, int kSplit,
    const float* __restrict__ bias,
    const float* __restrict__ E0, int ldE0,
    const float* __restrict__ E1, int ldE1,
    const float* __restrict__ E2, int ldE2)
{
    // k-chunk-major LDS: [k-chunk of 8][row 0..127][8 bf16]
    __shared__ __align__(16) short Ah[4][128][8];
    __shared__ __align__(16) short Al[4][128][8];
    __shared__ __align__(16) short Bh[4][128][8];
    __shared__ __align__(16) short Bl[4][128][8];

    const int tid  = threadIdx.x;
    const int lane = tid & 63;
    const int w    = tid >> 6;
    const int wr   = w >> 1, wc = w & 1;      // wave 2x2 grid, 64x64 out each
    const int lr   = lane & 15, lk = lane >> 4;
    const int m0 = blockIdx.y * 128, n0 = blockIdx.x * 128;

    const int arow = tid & 127;
    const int ksel = tid >> 7;                 // 0 or 1
    const int cA   = ksel * 2;                 // chunk base (k/8)

    f32x4 acc[4][4];
    #pragma unroll
    for (int i = 0; i < 4; i++)
        #pragma unroll
        for (int j = 0; j < 4; j++)
            acc[i][j] = (f32x4){0.f, 0.f, 0.f, 0.f};

    for (int k0 = 0; k0 < K; k0 += 32) {
        const float* Asrc = A; int kb = k0;
        if constexpr (MODE == 4) {
            if (k0 >= kSplit) { Asrc = A2; kb = k0 - kSplit; }
        }
        // ---- global loads ----
        const float* ap = &Asrc[(size_t)(m0 + arow) * lda + kb + ksel * 16];
        F4 f[4];
        #pragma unroll
        for (int q = 0; q < 4; q++) f[q].v = *(const float4*)(ap + q * 4);

        int4 wh0, wh1, wl0, wl1;
        if constexpr (PRE) {
            const size_t woff = (size_t)(n0 + arow) * K + k0 + ksel * 16;
            wh0 = *(const int4*)(Wh + woff);
            wh1 = *(const int4*)(Wh + woff + 8);
            wl0 = *(const int4*)(Wl + woff);
            wl1 = *(const int4*)(Wl + woff + 8);
        } else {
            const float* wpf = &Wf[(size_t)(n0 + arow) * K + k0 + ksel * 16];
            F4 g[4];
            #pragma unroll
            for (int q = 0; q < 4; q++) g[q].v = *(const float4*)(wpf + q * 4);
            S8 H0, H1, L0, L1;
            #pragma unroll
            for (int e = 0; e < 8; e++) {
                cvt2(g[e >> 2].a[e & 3],       H0.s[e], L0.s[e]);
                cvt2(g[2 + (e >> 2)].a[e & 3], H1.s[e], L1.s[e]);
            }
            wh0 = H0.v; wh1 = H1.v; wl0 = L0.v; wl1 = L1.v;
        }
        // ---- split A fp32 -> hi/lo bf16 ----
        S8 h0, h1, l0, l1;
        #pragma unroll
        for (int e = 0; e < 8; e++) {
            cvt2(f[e >> 2].a[e & 3],       h0.s[e], l0.s[e]);
            cvt2(f[2 + (e >> 2)].a[e & 3], h1.s[e], l1.s[e]);
        }
        __syncthreads();   // previous iteration's LDS reads done
        *(int4*)&Ah[cA][arow][0]     = h0.v;
        *(int4*)&Ah[cA + 1][arow][0] = h1.v;
        *(int4*)&Al[cA][arow][0]     = l0.v;
        *(int4*)&Al[cA + 1][arow][0] = l1.v;
        *(int4*)&Bh[cA][arow][0]     = wh0.x == wh0.x ? wh0 : wh0;
        *(int4*)&Bh[cA][arow][0]     = wh0;
        *(int4*)&Bh[cA + 1][arow][0] = wh1;
        *(int4*)&Bl[cA][arow][0]     = wl0;
        *(int4*)&Bl[cA + 1][arow][0] = wl1;
        __syncthreads();
        // ---- fragments + 3-term MFMA ----
        bf16x8 av[4], au[4], bv[4], bu[4];
        #pragma unroll
        for (int fi = 0; fi < 4; fi++) {
            av[fi] = *(const bf16x8*)&Ah[lk][wr * 64 + fi * 16 + lr][0];
            au[fi] = *(const bf16x8*)&Al[lk][wr * 64 + fi * 16 + lr][0];
            bv[fi] = *(const bf16x8*)&Bh[lk][wc * 64 + fi * 16 + lr][0];
            bu[fi] = *(const bf16x8*)&Bl[lk][wc * 64 + fi * 16 + lr][0];
        }
        #pragma unroll
        for (int i = 0; i < 4; i++)
            #pragma unroll
            for (int j = 0; j < 4; j++) {
                acc[i][j] = __builtin_amdgcn_mfma_f32_16x16x32_bf16(av[i], bv[j], acc[i][j], 0, 0, 0);
                acc[i][j] = __builtin_amdgcn_mfma_f32_16x16x32_bf16(av[i], bu[j], acc[i][j], 0, 0, 0);
                acc[i][j] = __builtin_amdgcn_mfma_f32_16x16x32_bf16(au[i], bv[j], acc[i][j], 0, 0, 0);
            }
    }

    // ---- epilogue: C/D layout col=lane&15, row=(lane>>4)*4+reg ----
    #pragma unroll
    for (int i = 0; i < 4; i++) {
        #pragma unroll
        for (int j = 0; j < 4; j++) {
            #pragma unroll
            for (int v = 0; v < 4; v++) {
                const size_t r = (size_t)(m0 + wr * 64 + i * 16 + lk * 4 + v);
                const int c = n0 + wc * 64 + j * 16 + lr;
                float val = acc[i][j][v];
                if constexpr (MODE == 1) {
                    val = silu(val);
                } else if constexpr (MODE == 2) {
                    val = C[r * ldc + c] * val;
                } else if constexpr (MODE == 3) {
                    const float g = sigm(val + bias[c]);
                    val = g * E0[r * ldE0 + c] + (1.0f - g) * E1[r * ldE1 + c];
                } else if constexpr (MODE == 4) {
                    const float g = sigm(val);
                    val = E0[r * ldE0 + c] + g * E1[r * ldE1 + c] + (1.0f - g) * E2[r * ldE2 + c];
                } else if constexpr (MODE == 6) {
                    val = C[r * ldc + c] + val;
                }
                C[r * ldc + c] = val;
            }
        }
    }
}

// host-side dispatch helper (branches on pre-split availability)
template<int MODE>
static inline void launch_gemm(bool pre, dim3 grid, hipStream_t stream,
    const float* A, const float* A2, int lda,
    const short* Wh, const short* Wl, const float* Wf,
    float* C, int ldc, int K, int kSplit,
    const float* bias,
    const float* E0, int ldE0, const float* E1, int ldE1, const float* E2, int ldE2)
{
    if (pre)
        gemm_m3_k<MODE, 1><<<grid, dim3(256), 0, stream>>>(A, A2, lda, Wh, Wl, Wf, C, ldc,
                                                           K, kSplit, bias, E0, ldE0, E1, ldE1, E2, ldE2);
    else
        gemm_m3_k<MODE, 0><<<grid, dim3(256), 0, stream>>>(A, A2, lda, Wh, Wl, Wf, C, ldc,
                                                           K, kSplit, bias, E0, ldE0, E1, ldE1, E2, ldE2);
}

// ---------------------------------------------------------------------------
extern "C" void kernel_launch(void* const* d_in, const int* in_sizes, int n_in,
                              void* d_out, int out_size, void* d_ws, size_t ws_size,
                              hipStream_t stream)
{
    const float* x           = (const float*)d_in[0];
    const float* qkv_w       = (const float*)d_in[1];
    const float* out_proj_w  = (const float*)d_in[2];
    const float* out_gate_w  = (const float*)d_in[3];
    const float* out_gate_b  = (const float*)d_in[4];
    const float* decay_param = (const float*)d_in[5];
    const float* conv_w      = (const float*)d_in[6];
    const float* conv_b      = (const float*)d_in[7];
    const float* pw_w        = (const float*)d_in[8];
    const float* gate_w      = (const float*)d_in[9];
    const float* w1          = (const float*)d_in[10];
    const float* w2          = (const float*)d_in[11];
    const float* w3          = (const float*)d_in[12];
    const float* norm1_w     = (const float*)d_in[13];
    const float* norm2_w     = (const float*)d_in[14];
    float* OUT = (float*)d_out;

    // ---- workspace layout: 4 fp32 planes of 32MB; d_out is the 5th plane ----
    float* ws = (float*)d_ws;
    const size_t S8 = (size_t)Mrows * HIDc;   // 8,388,608 floats = 32MB
    float* P0 = ws;
    float* P1 = P0 + S8;
    float* P2 = P1 + S8;
    float* P3 = P2 + S8;

    // optional pre-split bf16 weight region after the 4 planes
    constexpr size_t SZ_QKV  = (size_t)3 * HIDc * HIDc;   // 3,145,728
    constexpr size_t SZ_SQ   = (size_t)HIDc * HIDc;       // 1,048,576
    constexpr size_t SZ_GATE = (size_t)2 * HIDc * HIDc;   // 2,097,152
    constexpr size_t SZ_W1   = (size_t)INTERc * HIDc;     // 2,883,584
    constexpr size_t W_ELEMS = SZ_QKV + 3 * SZ_SQ + SZ_GATE + 3 * SZ_W1;  // 17,039,360
    const size_t base_bytes = 4 * S8 * sizeof(float);             // 134,217,728
    const size_t pre_bytes  = base_bytes + 2 * W_ELEMS * sizeof(short); // ~202.4MB
    const bool pre = (ws_size >= pre_bytes);

    short* wb = (short*)(ws + 4 * S8);
    short* qkv_h = wb;                 short* qkv_l = qkv_h + SZ_QKV;
    short* pw_h  = qkv_l + SZ_QKV;     short* pw_l  = pw_h  + SZ_SQ;
    short* og_h  = pw_l  + SZ_SQ;      short* og_l  = og_h  + SZ_SQ;
    short* op_h  = og_l  + SZ_SQ;      short* op_l  = op_h  + SZ_SQ;
    short* ga_h  = op_l  + SZ_SQ;      short* ga_l  = ga_h  + SZ_GATE;
    short* w1_h  = ga_l  + SZ_GATE;    short* w1_l  = w1_h  + SZ_W1;
    short* w2_h  = w1_l  + SZ_W1;      short* w2_l  = w2_h  + SZ_W1;
    short* w3_h  = w2_l  + SZ_W1;      short* w3_l  = w3_h  + SZ_W1;

    const dim3 blk(256);
    const dim3 g8(8, Mrows / 128);    // N=1024
    const dim3 g22(22, Mrows / 128);  // N=2816

    if (pre) {
        wsplit_k<<<(int)(SZ_QKV / 4 / 256), blk, 0, stream>>>(qkv_w, qkv_h, qkv_l, (int)(SZ_QKV / 4));
        wsplit_k<<<(int)(SZ_SQ  / 4 / 256), blk, 0, stream>>>(pw_w,  pw_h,  pw_l,  (int)(SZ_SQ  / 4));
        wsplit_k<<<(int)(SZ_SQ  / 4 / 256), blk, 0, stream>>>(out_gate_w, og_h, og_l, (int)(SZ_SQ / 4));
        wsplit_k<<<(int)(SZ_SQ  / 4 / 256), blk, 0, stream>>>(out_proj_w, op_h, op_l, (int)(SZ_SQ / 4));
        wsplit_k<<<(int)(SZ_GATE/ 4 / 256), blk, 0, stream>>>(gate_w, ga_h, ga_l, (int)(SZ_GATE / 4));
        wsplit_k<<<(int)(SZ_W1  / 4 / 256), blk, 0, stream>>>(w1, w1_h, w1_l, (int)(SZ_W1 / 4));
        wsplit_k<<<(int)(SZ_W1  / 4 / 256), blk, 0, stream>>>(w2, w2_h, w2_l, (int)(SZ_W1 / 4));
        wsplit_k<<<(int)(SZ_W1  / 4 / 256), blk, 0, stream>>>(w3, w3_h, w3_l, (int)(SZ_W1 / 4));
    }

    // 1. h = rmsnorm(x, norm1_w) -> P0
    rmsnorm_k<<<Mrows, blk, 0, stream>>>(x, norm1_w, P0);
    // 2. conv + bias + silu  (P0 -> P1)
    conv_k<<<Mrows, blk, 0, stream>>>(P0, conv_w, conv_b, P1);
    // 3. local = conv_silu @ pw_w^T  (P1 -> P2)
    launch_gemm<0>(pre, g8, stream, P1, nullptr, HIDc, pw_h, pw_l, pw_w, P2, HIDc,
                   HIDc, 0, nullptr, nullptr, 0, nullptr, 0, nullptr, 0);
    // 4. q,k,v = h @ qkv_w^T  (P0 -> q=P1, k=P3, v=OUT)
    launch_gemm<0>(pre, g8, stream, P0, nullptr, HIDc, qkv_h, qkv_l, qkv_w, P1, HIDc,
                   HIDc, 0, nullptr, nullptr, 0, nullptr, 0, nullptr, 0);
    launch_gemm<0>(pre, g8, stream, P0, nullptr, HIDc,
                   qkv_h + SZ_SQ, qkv_l + SZ_SQ, qkv_w + SZ_SQ, P3, HIDc,
                   HIDc, 0, nullptr, nullptr, 0, nullptr, 0, nullptr, 0);
    launch_gemm<0>(pre, g8, stream, P0, nullptr, HIDc,
                   qkv_h + 2 * SZ_SQ, qkv_l + 2 * SZ_SQ, qkv_w + 2 * SZ_SQ, OUT, HIDc,
                   HIDc, 0, nullptr, nullptr, 0, nullptr, 0, nullptr, 0);
    // 5a. chunk-local scans: k(P3) -> skv_loc IN-PLACE; sks_loc -> P0 (free)
    scan1_k<<<Bc * NHc * NC, dim3(64), 0, stream>>>(P3, OUT, P0, decay_param);
    // 5b. carry combine + output: o over q (P1) IN-PLACE
    scan2_k<<<Bc * NHc * NC, dim3(64), 0, stream>>>(P1, P3, P0, decay_param);
    // 6. out-gate: g = sigm(o@Wg^T + b); o2 = g*o + (1-g)*v   (o=P1, v=OUT -> P0)
    launch_gemm<3>(pre, g8, stream, P1, nullptr, HIDc, og_h, og_l, out_gate_w, P0, HIDc,
                   HIDc, 0, out_gate_b, P1, HIDc, OUT, HIDc, nullptr, 0);
    // 7. attn = o2 @ out_proj_w^T  (P0 -> P3)
    launch_gemm<0>(pre, g8, stream, P0, nullptr, HIDc, op_h, op_l, out_proj_w, P3, HIDc,
                   HIDc, 0, nullptr, nullptr, 0, nullptr, 0, nullptr, 0);
    // 8. gmix = sigm([local,attn]@gate_w^T); x1 = x + g*local + (1-g)*attn (-> OUT)
    launch_gemm<4>(pre, g8, stream, P2, P3, HIDc, ga_h, ga_l, gate_w, OUT, HIDc,
                   2 * HIDc, HIDc, nullptr, x, HIDc, P2, HIDc, P3, HIDc);
    // 9. h2 = rmsnorm(x1, norm2_w)  (OUT -> P0)
    rmsnorm_k<<<Mrows, blk, 0, stream>>>(OUT, norm2_w, P0);
    // 10. t1 = silu(h2 @ w1^T)  (-> P1 span, ld 2816; fits in P1..P3 = 96MB)
    launch_gemm<1>(pre, g22, stream, P0, nullptr, HIDc, w1_h, w1_l, w1, P1, INTERc,
                   HIDc, 0, nullptr, nullptr, 0, nullptr, 0, nullptr, 0);
    // 11. u = t1 * (h2 @ w2^T)  (RMW P1 span)
    launch_gemm<2>(pre, g22, stream, P0, nullptr, HIDc, w2_h, w2_l, w2, P1, INTERc,
                   HIDc, 0, nullptr, nullptr, 0, nullptr, 0, nullptr, 0);
    // 12. OUT = x1 + u @ w3^T  (RMW add into d_out)
    launch_gemm<6>(pre, g8, stream, P1, nullptr, INTERc, w3_h, w3_l, w3, OUT, HIDc,
                   INTERc, 0, nullptr, nullptr, 0, nullptr, 0, nullptr, 0);
}

// Round 5
// 1402.761 us; speedup vs baseline: 2.0231x; 1.2805x over previous
//
#include <hip/hip_runtime.h>
#include <math.h>

static constexpr int Bc    = 4;
static constexpr int Tc    = 2048;
static constexpr int HIDc  = 1024;
static constexpr int NHc   = 8;
static constexpr int HDc   = 128;
static constexpr int Mrows = Bc * Tc;          // 8192
static constexpr int INTERc= 2816;
static constexpr int CH    = 64;               // scan chunk length
static constexpr int NC    = Tc / CH;          // 32 chunks

typedef _Float16 f16;
typedef __attribute__((ext_vector_type(8))) _Float16 f16x8;
typedef __attribute__((ext_vector_type(4))) float f32x4;
typedef unsigned short u16;

union H8 { f16 h[8]; int4 v; u16 u[8]; };
union H4 { f16 h[4]; int2 v; u16 u[4]; };
union F4 { float4 v; float a[4]; };

static __device__ __forceinline__ float sigm(float x) { return 1.0f / (1.0f + expf(-x)); }
static __device__ __forceinline__ float silu(float x) { return x * sigm(x); }
static __device__ __forceinline__ float elu1(float x) { return x > 0.0f ? x + 1.0f : expf(x); }

static __device__ __forceinline__ float h2f(u16 u){ f16 h; __builtin_memcpy(&h,&u,2); return (float)h; }
static __device__ __forceinline__ u16 f2h(float x){ f16 h=(f16)x; u16 u; __builtin_memcpy(&u,&h,2); return u; }
static __device__ __forceinline__ float rec2(u16 h, u16 l){ return h2f(h) + h2f(l); }
static __device__ __forceinline__ void fsplit(float v, u16& h, u16& l){ h = f2h(v); l = f2h(v - h2f(h)); }

// ---------------------------------------------------------------------------
// Weight convert: fp32[n] -> fp16[n] (single term)
// ---------------------------------------------------------------------------
__global__ __launch_bounds__(256) void wcvt_k(const float* __restrict__ src,
                                              u16* __restrict__ dst, int n8)
{
    const int i = blockIdx.x * 256 + threadIdx.x;
    if (i >= n8) return;
    F4 a, b; a.v = ((const float4*)src)[i * 2]; b.v = ((const float4*)src)[i * 2 + 1];
    H8 o;
    #pragma unroll
    for (int u = 0; u < 4; u++) { o.h[u] = (f16)a.a[u]; o.h[4 + u] = (f16)b.a[u]; }
    ((int4*)dst)[i] = o.v;
}

// ---------------------------------------------------------------------------
// RMSNorm; INPAIR=0: x fp32 real.  INPAIR=1: x fp16-pair.  Output fp16-pair.
// One block per row, 256 threads, 4 elems/thread.
// ---------------------------------------------------------------------------
template<int INPAIR>
__global__ __launch_bounds__(256) void rmsnorm_k(const float* __restrict__ xf,
                                                 const u16* __restrict__ xhi,
                                                 const u16* __restrict__ xlo,
                                                 const float* __restrict__ w,
                                                 u16* __restrict__ ohi,
                                                 u16* __restrict__ olo)
{
    const int row = blockIdx.x;
    const int tid = threadIdx.x;
    const size_t off = (size_t)row * HIDc + tid * 4;
    float xv[4];
    if constexpr (INPAIR) {
        H4 H, L;
        H.v = *(const int2*)(xhi + off);
        L.v = *(const int2*)(xlo + off);
        #pragma unroll
        for (int u = 0; u < 4; u++) xv[u] = (float)H.h[u] + (float)L.h[u];
    } else {
        F4 f; f.v = *(const float4*)(xf + off);
        #pragma unroll
        for (int u = 0; u < 4; u++) xv[u] = f.a[u];
    }
    float ss = xv[0]*xv[0] + xv[1]*xv[1] + xv[2]*xv[2] + xv[3]*xv[3];
    #pragma unroll
    for (int o = 32; o > 0; o >>= 1) ss += __shfl_xor(ss, o);
    __shared__ float sred[4];
    if ((tid & 63) == 0) sred[tid >> 6] = ss;
    __syncthreads();
    const float tot = sred[0] + sred[1] + sred[2] + sred[3];
    const float scale = rsqrtf(tot * (1.0f / (float)HIDc) + 1e-6f);
    F4 wv; wv.v = *(const float4*)(w + tid * 4);
    H4 OH, OL;
    #pragma unroll
    for (int u = 0; u < 4; u++) {
        u16 hh, ll; fsplit(xv[u] * scale * wv.a[u], hh, ll);
        OH.u[u] = hh; OL.u[u] = ll;
    }
    *(int2*)(ohi + off) = OH.v;
    *(int2*)(olo + off) = OL.v;
}

// ---------------------------------------------------------------------------
// Depthwise causal conv (KS=4) + bias + SiLU.  pair-in, pair-out.
// ---------------------------------------------------------------------------
__global__ __launch_bounds__(256) void conv_k(const u16* __restrict__ hhi,
                                              const u16* __restrict__ hlo,
                                              const float* __restrict__ cw,
                                              const float* __restrict__ cb,
                                              u16* __restrict__ ohi,
                                              u16* __restrict__ olo)
{
    const int row = blockIdx.x;
    const int t   = row & (Tc - 1);
    const int ch4 = threadIdx.x * 4;
    const float* wp = cw + (size_t)ch4 * 4;
    F4 bias; bias.v = *(const float4*)(cb + ch4);
    F4 acc;
    #pragma unroll
    for (int u = 0; u < 4; u++) acc.a[u] = bias.a[u];
    #pragma unroll
    for (int j = 0; j < 4; j++) {
        const int tt = t - 3 + j;
        if (tt >= 0) {
            const size_t off = ((size_t)row + j - 3) * HIDc + ch4;
            H4 H, L;
            H.v = *(const int2*)(hhi + off);
            L.v = *(const int2*)(hlo + off);
            #pragma unroll
            for (int u = 0; u < 4; u++) acc.a[u] += ((float)H.h[u] + (float)L.h[u]) * wp[u * 4 + j];
        }
    }
    H4 OH, OL;
    #pragma unroll
    for (int u = 0; u < 4; u++) {
        u16 hh, ll; fsplit(silu(acc.a[u]), hh, ll);
        OH.u[u] = hh; OL.u[u] = ll;
    }
    const size_t off = (size_t)row * HIDc + ch4;
    *(int2*)(ohi + off) = OH.v;
    *(int2*)(olo + off) = OL.v;
}

// ---------------------------------------------------------------------------
// Chunked scan step 1: local scans.  k pair -> skv pair IN PLACE; sks -> pair.
// ---------------------------------------------------------------------------
__global__ __launch_bounds__(64) void scan1_k(u16* __restrict__ khi, u16* __restrict__ klo,
                                              const u16* __restrict__ vhi, const u16* __restrict__ vlo,
                                              u16* __restrict__ shi, u16* __restrict__ slo,
                                              const float* __restrict__ dp)
{
    const int bid = blockIdx.x;
    const int c   = bid & (NC - 1);
    const int bh  = bid >> 5;
    const int b   = bh >> 3, hh = bh & 7;
    const int lane = threadIdx.x;
    const float dec = sigm(dp[hh]);
    const size_t base = (size_t)b * Tc * HIDc + (size_t)(c * CH) * HIDc + hh * HDc + lane * 2;
    float skv0 = 0.f, skv1 = 0.f, sks0 = 0.f, sks1 = 0.f;
    for (int t = 0; t < CH; t++) {
        const size_t p = base + (size_t)t * HIDc;
        const unsigned kh = *(const unsigned*)(khi + p);
        const unsigned kl = *(const unsigned*)(klo + p);
        const unsigned vh = *(const unsigned*)(vhi + p);
        const unsigned vl = *(const unsigned*)(vlo + p);
        const float kx = elu1(rec2((u16)kh, (u16)kl));
        const float ky = elu1(rec2((u16)(kh >> 16), (u16)(kl >> 16)));
        const float vx = rec2((u16)vh, (u16)vl);
        const float vy = rec2((u16)(vh >> 16), (u16)(vl >> 16));
        skv0 = dec * skv0 + kx * vx;
        skv1 = dec * skv1 + ky * vy;
        sks0 = dec * sks0 + kx;
        sks1 = dec * sks1 + ky;
        u16 h0, l0, h1, l1;
        fsplit(skv0, h0, l0); fsplit(skv1, h1, l1);
        *(unsigned*)(khi + p) = (unsigned)h0 | ((unsigned)h1 << 16);
        *(unsigned*)(klo + p) = (unsigned)l0 | ((unsigned)l1 << 16);
        fsplit(sks0, h0, l0); fsplit(sks1, h1, l1);
        *(unsigned*)(shi + p) = (unsigned)h0 | ((unsigned)h1 << 16);
        *(unsigned*)(slo + p) = (unsigned)l0 | ((unsigned)l1 << 16);
    }
}

// ---------------------------------------------------------------------------
// Chunked scan step 2: carry combine + output.  q pair -> o pair IN PLACE.
// ---------------------------------------------------------------------------
__global__ __launch_bounds__(64) void scan2_k(u16* __restrict__ qhi, u16* __restrict__ qlo,
                                              const u16* __restrict__ skvhi, const u16* __restrict__ skvlo,
                                              const u16* __restrict__ skshi, const u16* __restrict__ skslo,
                                              const float* __restrict__ dp)
{
    const int bid = blockIdx.x;
    const int c   = bid & (NC - 1);
    const int bh  = bid >> 5;
    const int b   = bh >> 3, hh = bh & 7;
    const int lane = threadIdx.x;
    const float dec = sigm(dp[hh]);
    float dCH = dec;
    #pragma unroll
    for (int i = 0; i < 6; i++) dCH *= dCH;      // dec^64
    const size_t rowbase = (size_t)b * Tc * HIDc + hh * HDc + lane * 2;

    float ckv0 = 0.f, ckv1 = 0.f, cks0 = 0.f, cks1 = 0.f;
    for (int j = 0; j < c; j++) {
        const size_t p = rowbase + (size_t)(j * CH + CH - 1) * HIDc;
        const unsigned ah = *(const unsigned*)(skvhi + p);
        const unsigned al = *(const unsigned*)(skvlo + p);
        const unsigned bh2 = *(const unsigned*)(skshi + p);
        const unsigned bl2 = *(const unsigned*)(skslo + p);
        ckv0 = ckv0 * dCH + rec2((u16)ah, (u16)al);
        ckv1 = ckv1 * dCH + rec2((u16)(ah >> 16), (u16)(al >> 16));
        cks0 = cks0 * dCH + rec2((u16)bh2, (u16)bl2);
        cks1 = cks1 * dCH + rec2((u16)(bh2 >> 16), (u16)(bl2 >> 16));
    }

    const size_t cbase = rowbase + (size_t)(c * CH) * HIDc;
    float pw = dec;
    for (int t = 0; t < CH; t++) {
        const size_t p = cbase + (size_t)t * HIDc;
        const unsigned qh = *(const unsigned*)(qhi + p);
        const unsigned ql = *(const unsigned*)(qlo + p);
        const unsigned ah = *(const unsigned*)(skvhi + p);
        const unsigned al = *(const unsigned*)(skvlo + p);
        const unsigned bh2 = *(const unsigned*)(skshi + p);
        const unsigned bl2 = *(const unsigned*)(skslo + p);
        const float qx = elu1(rec2((u16)qh, (u16)ql));
        const float qy = elu1(rec2((u16)(qh >> 16), (u16)(ql >> 16)));
        const float skv0 = rec2((u16)ah, (u16)al) + pw * ckv0;
        const float skv1 = rec2((u16)(ah >> 16), (u16)(al >> 16)) + pw * ckv1;
        const float sks0 = rec2((u16)bh2, (u16)bl2) + pw * cks0;
        const float sks1 = rec2((u16)(bh2 >> 16), (u16)(bl2 >> 16)) + pw * cks1;
        float part = qx * sks0 + qy * sks1;
        #pragma unroll
        for (int o = 32; o > 0; o >>= 1) part += __shfl_xor(part, o);
        const float inv = 1.0f / fmaxf(part, 1e-6f);
        u16 h0, l0, h1, l1;
        fsplit(qx * skv0 * inv, h0, l0);
        fsplit(qy * skv1 * inv, h1, l1);
        *(unsigned*)(qhi + p) = (unsigned)h0 | ((unsigned)h1 << 16);
        *(unsigned*)(qlo + p) = (unsigned)l0 | ((unsigned)l1 << 16);
        pw *= dec;
    }
}

// ---------------------------------------------------------------------------
// fp16-pair MFMA GEMM: C = A @ W^T, A exact (hi+lo fp16 pair), W single fp16.
// 2 MFMA per (i,j) frag pair.  128x128 tile, BK=32, 4 waves, 4x4 16x16x32.
// MODE 0: C = acc (pair out)
// MODE 1: C = silu(acc) (pair out)
// MODE 2: C = rec(Cpair) * acc (pair RMW)
// MODE 3: g = sigm(acc+bias); C = g*rec(E0) + (1-g)*rec(E1) (pair out)
// MODE 4: g = sigm(acc); C = E0f + g*rec(E1) + (1-g)*rec(E2) (pair out; A2 at kSplit)
// MODE 6: Cout = rec(Cpair) + acc (REAL fp32 out to separate buffer)
// ---------------------------------------------------------------------------
template<int MODE, int PRE>
__global__ __launch_bounds__(256) void gemm_f16_k(
    const u16* __restrict__ Ahi, const u16* __restrict__ Alo,
    const u16* __restrict__ A2hi, const u16* __restrict__ A2lo, int lda,
    const u16* __restrict__ Wh, const float* __restrict__ Wf,
    float* __restrict__ Cout,
    u16* __restrict__ Chi, u16* __restrict__ Clo, int ldc,
    int K, int kSplit, const float* __restrict__ bias,
    const float* __restrict__ E0f,
    const u16* __restrict__ E0hi, const u16* __restrict__ E0lo, int ldE0,
    const u16* __restrict__ E1hi, const u16* __restrict__ E1lo, int ldE1,
    const u16* __restrict__ E2hi, const u16* __restrict__ E2lo, int ldE2)
{
    // k-chunk-major LDS, row dim padded 128->129 to spread lk-groups over banks
    __shared__ __align__(16) u16 Ah[4][129][8];
    __shared__ __align__(16) u16 Al[4][129][8];
    __shared__ __align__(16) u16 Bs[4][129][8];

    const int tid  = threadIdx.x;
    const int lane = tid & 63;
    const int w    = tid >> 6;
    const int wr   = w >> 1, wc = w & 1;
    const int lr   = lane & 15, lk = lane >> 4;
    const int m0 = blockIdx.y * 128, n0 = blockIdx.x * 128;

    const int arow = tid & 127;
    const int ksel = tid >> 7;
    const int cA   = ksel * 2;

    f32x4 acc[4][4];
    #pragma unroll
    for (int i = 0; i < 4; i++)
        #pragma unroll
        for (int j = 0; j < 4; j++)
            acc[i][j] = (f32x4){0.f, 0.f, 0.f, 0.f};

    for (int k0 = 0; k0 < K; k0 += 32) {
        const u16* ah = Ahi; const u16* al = Alo; int kb = k0;
        if constexpr (MODE == 4) {
            if (k0 >= kSplit) { ah = A2hi; al = A2lo; kb = k0 - kSplit; }
        }
        const size_t aoff = (size_t)(m0 + arow) * lda + kb + ksel * 16;
        const int4 a0 = *(const int4*)(ah + aoff);
        const int4 a1 = *(const int4*)(ah + aoff + 8);
        const int4 l0 = *(const int4*)(al + aoff);
        const int4 l1 = *(const int4*)(al + aoff + 8);
        int4 w0, w1;
        if constexpr (PRE) {
            const size_t woff = (size_t)(n0 + arow) * K + k0 + ksel * 16;
            w0 = *(const int4*)(Wh + woff);
            w1 = *(const int4*)(Wh + woff + 8);
        } else {
            const float* wpf = Wf + (size_t)(n0 + arow) * K + k0 + ksel * 16;
            F4 g[4];
            #pragma unroll
            for (int q = 0; q < 4; q++) g[q].v = *(const float4*)(wpf + q * 4);
            H8 W0, W1;
            #pragma unroll
            for (int e = 0; e < 8; e++) {
                W0.h[e] = (f16)g[e >> 2].a[e & 3];
                W1.h[e] = (f16)g[2 + (e >> 2)].a[e & 3];
            }
            w0 = W0.v; w1 = W1.v;
        }
        __syncthreads();   // previous iteration's LDS reads done
        *(int4*)&Ah[cA][arow][0]     = a0;
        *(int4*)&Ah[cA + 1][arow][0] = a1;
        *(int4*)&Al[cA][arow][0]     = l0;
        *(int4*)&Al[cA + 1][arow][0] = l1;
        *(int4*)&Bs[cA][arow][0]     = w0;
        *(int4*)&Bs[cA + 1][arow][0] = w1;
        __syncthreads();
        f16x8 av[4], au[4], bv[4];
        #pragma unroll
        for (int fi = 0; fi < 4; fi++) {
            av[fi] = *(const f16x8*)&Ah[lk][wr * 64 + fi * 16 + lr][0];
            au[fi] = *(const f16x8*)&Al[lk][wr * 64 + fi * 16 + lr][0];
            bv[fi] = *(const f16x8*)&Bs[lk][wc * 64 + fi * 16 + lr][0];
        }
        #pragma unroll
        for (int i = 0; i < 4; i++)
            #pragma unroll
            for (int j = 0; j < 4; j++) {
                acc[i][j] = __builtin_amdgcn_mfma_f32_16x16x32_f16(av[i], bv[j], acc[i][j], 0, 0, 0);
                acc[i][j] = __builtin_amdgcn_mfma_f32_16x16x32_f16(au[i], bv[j], acc[i][j], 0, 0, 0);
            }
    }

    // epilogue: C/D layout col=lane&15, row=(lane>>4)*4+reg
    #pragma unroll
    for (int i = 0; i < 4; i++) {
        #pragma unroll
        for (int j = 0; j < 4; j++) {
            #pragma unroll
            for (int v = 0; v < 4; v++) {
                const size_t r = (size_t)(m0 + wr * 64 + i * 16 + lk * 4 + v);
                const int c = n0 + wc * 64 + j * 16 + lr;
                const size_t idx = r * (size_t)ldc + c;
                float val = acc[i][j][v];
                if constexpr (MODE == 1) {
                    val = silu(val);
                } else if constexpr (MODE == 2) {
                    val = rec2(Chi[idx], Clo[idx]) * val;
                } else if constexpr (MODE == 3) {
                    const float g = sigm(val + bias[c]);
                    const size_t i0 = r * (size_t)ldE0 + c, i1 = r * (size_t)ldE1 + c;
                    val = g * rec2(E0hi[i0], E0lo[i0]) + (1.0f - g) * rec2(E1hi[i1], E1lo[i1]);
                } else if constexpr (MODE == 4) {
                    const float g = sigm(val);
                    const size_t i1 = r * (size_t)ldE1 + c, i2 = r * (size_t)ldE2 + c;
                    val = E0f[r * (size_t)ldE0 + c] + g * rec2(E1hi[i1], E1lo[i1])
                          + (1.0f - g) * rec2(E2hi[i2], E2lo[i2]);
                } else if constexpr (MODE == 6) {
                    Cout[idx] = rec2(Chi[idx], Clo[idx]) + val;
                    continue;
                }
                u16 hh, ll; fsplit(val, hh, ll);
                Chi[idx] = hh; Clo[idx] = ll;
            }
        }
    }
}

template<int MODE>
static inline void launch_gemm(bool pre, dim3 grid, hipStream_t stream,
    const u16* Ahi, const u16* Alo, const u16* A2hi, const u16* A2lo, int lda,
    const u16* Wh, const float* Wf,
    float* Cout, u16* Chi, u16* Clo, int ldc, int K, int kSplit,
    const float* bias, const float* E0f,
    const u16* E0hi, const u16* E0lo, int ldE0,
    const u16* E1hi, const u16* E1lo, int ldE1,
    const u16* E2hi, const u16* E2lo, int ldE2)
{
    if (pre)
        gemm_f16_k<MODE, 1><<<grid, dim3(256), 0, stream>>>(Ahi, Alo, A2hi, A2lo, lda, Wh, Wf,
            Cout, Chi, Clo, ldc, K, kSplit, bias, E0f, E0hi, E0lo, ldE0, E1hi, E1lo, ldE1, E2hi, E2lo, ldE2);
    else
        gemm_f16_k<MODE, 0><<<grid, dim3(256), 0, stream>>>(Ahi, Alo, A2hi, A2lo, lda, Wh, Wf,
            Cout, Chi, Clo, ldc, K, kSplit, bias, E0f, E0hi, E0lo, ldE0, E1hi, E1lo, ldE1, E2hi, E2lo, ldE2);
}

// ---------------------------------------------------------------------------
extern "C" void kernel_launch(void* const* d_in, const int* in_sizes, int n_in,
                              void* d_out, int out_size, void* d_ws, size_t ws_size,
                              hipStream_t stream)
{
    const float* x           = (const float*)d_in[0];
    const float* qkv_w       = (const float*)d_in[1];
    const float* out_proj_w  = (const float*)d_in[2];
    const float* out_gate_w  = (const float*)d_in[3];
    const float* out_gate_b  = (const float*)d_in[4];
    const float* decay_param = (const float*)d_in[5];
    const float* conv_w      = (const float*)d_in[6];
    const float* conv_b      = (const float*)d_in[7];
    const float* pw_w        = (const float*)d_in[8];
    const float* gate_w      = (const float*)d_in[9];
    const float* w1          = (const float*)d_in[10];
    const float* w2          = (const float*)d_in[11];
    const float* w3          = (const float*)d_in[12];
    const float* norm1_w     = (const float*)d_in[13];
    const float* norm2_w     = (const float*)d_in[14];
    float* OUT = (float*)d_out;

    // ---- plane map (each 32MB = S8 fp32 slots; pair = hi[S8 u16] + lo[S8 u16]) ----
    // P0: h -> sks -> o2 -> x1    P1: conv -> q/o -> t1/u (hi+lo span P1..P3)
    // P2: local                   P3: k/skv -> attn
    // OUT: v -> h2(scratch) -> final fp32
    float* ws = (float*)d_ws;
    const size_t S8 = (size_t)Mrows * HIDc;   // 8,388,608
    u16* P0h = (u16*)(ws + 0 * S8); u16* P0l = P0h + S8;
    u16* P1h = (u16*)(ws + 1 * S8); u16* P1l = P1h + S8;
    u16* P2h = (u16*)(ws + 2 * S8); u16* P2l = P2h + S8;
    u16* P3h = (u16*)(ws + 3 * S8); u16* P3l = P3h + S8;
    u16* OUTh = (u16*)OUT;          u16* OUTl = OUTh + S8;
    // t1/u spans P1..P3: hi then lo, each Mrows*INTER
    u16* T1h = P1h;                 u16* T1l = P1h + (size_t)Mrows * INTERc;

    // fp16 weights after the 4 planes (gated on ws_size)
    constexpr size_t SZ_QKV  = (size_t)3 * HIDc * HIDc;
    constexpr size_t SZ_SQ   = (size_t)HIDc * HIDc;
    constexpr size_t SZ_GATE = (size_t)2 * HIDc * HIDc;
    constexpr size_t SZ_W1   = (size_t)INTERc * HIDc;
    constexpr size_t W_ELEMS = SZ_QKV + 3 * SZ_SQ + SZ_GATE + 3 * SZ_W1;  // 17,039,360
    const bool pre = (ws_size >= 4 * S8 * sizeof(float) + W_ELEMS * sizeof(u16));

    u16* wb   = (u16*)(ws + 4 * S8);
    u16* qkvH = wb;
    u16* pwH  = qkvH + SZ_QKV;
    u16* ogH  = pwH  + SZ_SQ;
    u16* opH  = ogH  + SZ_SQ;
    u16* gaH  = opH  + SZ_SQ;
    u16* w1H  = gaH  + SZ_GATE;
    u16* w2H  = w1H  + SZ_W1;
    u16* w3H  = w2H  + SZ_W1;

    const dim3 blk(256);
    const dim3 g8(8, Mrows / 128);
    const dim3 g22(22, Mrows / 128);
    const u16* nu = nullptr;

    if (pre) {
        wcvt_k<<<(int)(SZ_QKV / 8 / 256), blk, 0, stream>>>(qkv_w, qkvH, (int)(SZ_QKV / 8));
        wcvt_k<<<(int)(SZ_SQ  / 8 / 256), blk, 0, stream>>>(pw_w,  pwH,  (int)(SZ_SQ  / 8));
        wcvt_k<<<(int)(SZ_SQ  / 8 / 256), blk, 0, stream>>>(out_gate_w, ogH, (int)(SZ_SQ / 8));
        wcvt_k<<<(int)(SZ_SQ  / 8 / 256), blk, 0, stream>>>(out_proj_w, opH, (int)(SZ_SQ / 8));
        wcvt_k<<<(int)(SZ_GATE/ 8 / 256), blk, 0, stream>>>(gate_w, gaH, (int)(SZ_GATE / 8));
        wcvt_k<<<(int)(SZ_W1  / 8 / 256), blk, 0, stream>>>(w1, w1H, (int)(SZ_W1 / 8));
        wcvt_k<<<(int)(SZ_W1  / 8 / 256), blk, 0, stream>>>(w2, w2H, (int)(SZ_W1 / 8));
        wcvt_k<<<(int)(SZ_W1  / 8 / 256), blk, 0, stream>>>(w3, w3H, (int)(SZ_W1 / 8));
    }

    // 1. h = rmsnorm(x) -> P0 pair
    rmsnorm_k<0><<<Mrows, blk, 0, stream>>>(x, nullptr, nullptr, norm1_w, P0h, P0l);
    // 2. conv(h) -> P1 pair
    conv_k<<<Mrows, blk, 0, stream>>>(P0h, P0l, conv_w, conv_b, P1h, P1l);
    // 3. local = conv @ pw^T -> P2 pair
    launch_gemm<0>(pre, g8, stream, P1h, P1l, nu, nu, HIDc, pwH, pw_w,
                   nullptr, P2h, P2l, HIDc, HIDc, 0, nullptr, nullptr,
                   nu, nu, 0, nu, nu, 0, nu, nu, 0);
    // 4. q,k,v = h @ qkv^T -> P1, P3, OUT pairs
    launch_gemm<0>(pre, g8, stream, P0h, P0l, nu, nu, HIDc, qkvH, qkv_w,
                   nullptr, P1h, P1l, HIDc, HIDc, 0, nullptr, nullptr,
                   nu, nu, 0, nu, nu, 0, nu, nu, 0);
    launch_gemm<0>(pre, g8, stream, P0h, P0l, nu, nu, HIDc, qkvH + SZ_SQ, qkv_w + SZ_SQ,
                   nullptr, P3h, P3l, HIDc, HIDc, 0, nullptr, nullptr,
                   nu, nu, 0, nu, nu, 0, nu, nu, 0);
    launch_gemm<0>(pre, g8, stream, P0h, P0l, nu, nu, HIDc, qkvH + 2 * SZ_SQ, qkv_w + 2 * SZ_SQ,
                   nullptr, OUTh, OUTl, HIDc, HIDc, 0, nullptr, nullptr,
                   nu, nu, 0, nu, nu, 0, nu, nu, 0);
    // 5a. local scans: skv over k (P3, in place); sks -> P0 (h dead)
    scan1_k<<<Bc * NHc * NC, dim3(64), 0, stream>>>(P3h, P3l, OUTh, OUTl, P0h, P0l, decay_param);
    // 5b. carry + output: o over q (P1, in place)
    scan2_k<<<Bc * NHc * NC, dim3(64), 0, stream>>>(P1h, P1l, P3h, P3l, P0h, P0l, decay_param);
    // 6. out-gate: g=sigm(o@og^T+b); o2 = g*o + (1-g)*v -> P0 pair (sks dead)
    launch_gemm<3>(pre, g8, stream, P1h, P1l, nu, nu, HIDc, ogH, out_gate_w,
                   nullptr, P0h, P0l, HIDc, HIDc, 0, out_gate_b, nullptr,
                   P1h, P1l, HIDc, OUTh, OUTl, HIDc, nu, nu, 0);
    // 7. attn = o2 @ op^T -> P3 pair (skv dead)
    launch_gemm<0>(pre, g8, stream, P0h, P0l, nu, nu, HIDc, opH, out_proj_w,
                   nullptr, P3h, P3l, HIDc, HIDc, 0, nullptr, nullptr,
                   nu, nu, 0, nu, nu, 0, nu, nu, 0);
    // 8. gate fusion: gmix=sigm([local,attn]@ga^T); x1 = x + g*local + (1-g)*attn -> P0 pair
    launch_gemm<4>(pre, g8, stream, P2h, P2l, P3h, P3l, HIDc, gaH, gate_w,
                   nullptr, P0h, P0l, HIDc, 2 * HIDc, HIDc, nullptr, x,
                   nu, nu, HIDc, P2h, P2l, HIDc, P3h, P3l, HIDc);
    // 9. h2 = rmsnorm(x1) -> OUT pair (v dead; OUT reused as scratch)
    rmsnorm_k<1><<<Mrows, blk, 0, stream>>>(nullptr, P0h, P0l, norm2_w, OUTh, OUTl);
    // 10. t1 = silu(h2 @ w1^T) -> T1 pair (spans P1..P3; q/local/attn dead)
    launch_gemm<1>(pre, g22, stream, OUTh, OUTl, nu, nu, HIDc, w1H, w1,
                   nullptr, T1h, T1l, INTERc, HIDc, 0, nullptr, nullptr,
                   nu, nu, 0, nu, nu, 0, nu, nu, 0);
    // 11. u = t1 * (h2 @ w2^T)  (pair RMW over T1)
    launch_gemm<2>(pre, g22, stream, OUTh, OUTl, nu, nu, HIDc, w2H, w2,
                   nullptr, T1h, T1l, INTERc, HIDc, 0, nullptr, nullptr,
                   nu, nu, 0, nu, nu, 0, nu, nu, 0);
    // 12. OUT = x1 + u @ w3^T  (read x1 pair from P0, write REAL fp32 to d_out)
    launch_gemm<6>(pre, g8, stream, T1h, T1l, nu, nu, INTERc, w3H, w3,
                   OUT, P0h, P0l, HIDc, INTERc, 0, nullptr, nullptr,
                   nu, nu, 0, nu, nu, 0, nu, nu, 0);
}

// Round 6
// 1285.378 us; speedup vs baseline: 2.2079x; 1.0913x over previous
//
#include <hip/hip_runtime.h>
#include <math.h>

static constexpr int Bc    = 4;
static constexpr int Tc    = 2048;
static constexpr int HIDc  = 1024;
static constexpr int NHc   = 8;
static constexpr int HDc   = 128;
static constexpr int Mrows = Bc * Tc;          // 8192
static constexpr int INTERc= 2816;
static constexpr int CH    = 64;               // scan chunk length
static constexpr int NC    = Tc / CH;          // 32 chunks

typedef _Float16 f16;
typedef __attribute__((ext_vector_type(8))) _Float16 f16x8;
typedef __attribute__((ext_vector_type(4))) float f32x4;
typedef unsigned short u16;

union H8 { f16 h[8]; int4 v; u16 u[8]; };
union H4 { f16 h[4]; int2 v; u16 u[4]; };
union F4 { float4 v; float a[4]; };

static __device__ __forceinline__ float sigm(float x) { return 1.0f / (1.0f + expf(-x)); }
static __device__ __forceinline__ float silu(float x) { return x * sigm(x); }
static __device__ __forceinline__ float elu1(float x) { return x > 0.0f ? x + 1.0f : expf(x); }

static __device__ __forceinline__ float h2f(u16 u){ f16 h; __builtin_memcpy(&h,&u,2); return (float)h; }
static __device__ __forceinline__ u16 f2h(float x){ f16 h=(f16)x; u16 u; __builtin_memcpy(&u,&h,2); return u; }
static __device__ __forceinline__ float rec2(u16 h, u16 l){ return h2f(h) + h2f(l); }
static __device__ __forceinline__ void fsplit(float v, u16& h, u16& l){ h = f2h(v); l = f2h(v - h2f(h)); }

// async global->LDS, 16B per lane; LDS dest = wave-uniform base + lane*16
static __device__ __forceinline__ void gld16(const u16* g, u16* l)
{
    __builtin_amdgcn_global_load_lds((const __attribute__((address_space(1))) void*)g,
                                     (__attribute__((address_space(3))) void*)l,
                                     16, 0, 0);
}

// ---------------------------------------------------------------------------
// Weight convert: fp32[n] -> fp16[n]
// ---------------------------------------------------------------------------
__global__ __launch_bounds__(256) void wcvt_k(const float* __restrict__ src,
                                              u16* __restrict__ dst, int n8)
{
    const int i = blockIdx.x * 256 + threadIdx.x;
    if (i >= n8) return;
    F4 a, b; a.v = ((const float4*)src)[i * 2]; b.v = ((const float4*)src)[i * 2 + 1];
    H8 o;
    #pragma unroll
    for (int u = 0; u < 4; u++) { o.h[u] = (f16)a.a[u]; o.h[4 + u] = (f16)b.a[u]; }
    ((int4*)dst)[i] = o.v;
}

// ---------------------------------------------------------------------------
// RMSNorm; INPAIR=0: x fp32.  INPAIR=1: x fp16-pair.  Output fp16-pair.
// ---------------------------------------------------------------------------
template<int INPAIR>
__global__ __launch_bounds__(256) void rmsnorm_k(const float* __restrict__ xf,
                                                 const u16* __restrict__ xhi,
                                                 const u16* __restrict__ xlo,
                                                 const float* __restrict__ w,
                                                 u16* __restrict__ ohi,
                                                 u16* __restrict__ olo)
{
    const int row = blockIdx.x;
    const int tid = threadIdx.x;
    const size_t off = (size_t)row * HIDc + tid * 4;
    float xv[4];
    if constexpr (INPAIR) {
        H4 H, L;
        H.v = *(const int2*)(xhi + off);
        L.v = *(const int2*)(xlo + off);
        #pragma unroll
        for (int u = 0; u < 4; u++) xv[u] = (float)H.h[u] + (float)L.h[u];
    } else {
        F4 f; f.v = *(const float4*)(xf + off);
        #pragma unroll
        for (int u = 0; u < 4; u++) xv[u] = f.a[u];
    }
    float ss = xv[0]*xv[0] + xv[1]*xv[1] + xv[2]*xv[2] + xv[3]*xv[3];
    #pragma unroll
    for (int o = 32; o > 0; o >>= 1) ss += __shfl_xor(ss, o);
    __shared__ float sred[4];
    if ((tid & 63) == 0) sred[tid >> 6] = ss;
    __syncthreads();
    const float tot = sred[0] + sred[1] + sred[2] + sred[3];
    const float scale = rsqrtf(tot * (1.0f / (float)HIDc) + 1e-6f);
    F4 wv; wv.v = *(const float4*)(w + tid * 4);
    H4 OH, OL;
    #pragma unroll
    for (int u = 0; u < 4; u++) {
        u16 hh, ll; fsplit(xv[u] * scale * wv.a[u], hh, ll);
        OH.u[u] = hh; OL.u[u] = ll;
    }
    *(int2*)(ohi + off) = OH.v;
    *(int2*)(olo + off) = OL.v;
}

// ---------------------------------------------------------------------------
// Depthwise causal conv (KS=4) + bias + SiLU.  pair-in, pair-out.
// ---------------------------------------------------------------------------
__global__ __launch_bounds__(256) void conv_k(const u16* __restrict__ hhi,
                                              const u16* __restrict__ hlo,
                                              const float* __restrict__ cw,
                                              const float* __restrict__ cb,
                                              u16* __restrict__ ohi,
                                              u16* __restrict__ olo)
{
    const int row = blockIdx.x;
    const int t   = row & (Tc - 1);
    const int ch4 = threadIdx.x * 4;
    const float* wp = cw + (size_t)ch4 * 4;
    F4 bias; bias.v = *(const float4*)(cb + ch4);
    F4 acc;
    #pragma unroll
    for (int u = 0; u < 4; u++) acc.a[u] = bias.a[u];
    #pragma unroll
    for (int j = 0; j < 4; j++) {
        const int tt = t - 3 + j;
        if (tt >= 0) {
            const size_t off = ((size_t)row + j - 3) * HIDc + ch4;
            H4 H, L;
            H.v = *(const int2*)(hhi + off);
            L.v = *(const int2*)(hlo + off);
            #pragma unroll
            for (int u = 0; u < 4; u++) acc.a[u] += ((float)H.h[u] + (float)L.h[u]) * wp[u * 4 + j];
        }
    }
    H4 OH, OL;
    #pragma unroll
    for (int u = 0; u < 4; u++) {
        u16 hh, ll; fsplit(silu(acc.a[u]), hh, ll);
        OH.u[u] = hh; OL.u[u] = ll;
    }
    const size_t off = (size_t)row * HIDc + ch4;
    *(int2*)(ohi + off) = OH.v;
    *(int2*)(olo + off) = OL.v;
}

// ---------------------------------------------------------------------------
// Chunked scan step 1: local scans.  k pair -> skv pair IN PLACE; sks -> pair.
// ---------------------------------------------------------------------------
__global__ __launch_bounds__(64) void scan1_k(u16* __restrict__ khi, u16* __restrict__ klo,
                                              const u16* __restrict__ vhi, const u16* __restrict__ vlo,
                                              u16* __restrict__ shi, u16* __restrict__ slo,
                                              const float* __restrict__ dp)
{
    const int bid = blockIdx.x;
    const int c   = bid & (NC - 1);
    const int bh  = bid >> 5;
    const int b   = bh >> 3, hh = bh & 7;
    const int lane = threadIdx.x;
    const float dec = sigm(dp[hh]);
    const size_t base = (size_t)b * Tc * HIDc + (size_t)(c * CH) * HIDc + hh * HDc + lane * 2;
    float skv0 = 0.f, skv1 = 0.f, sks0 = 0.f, sks1 = 0.f;
    for (int t = 0; t < CH; t++) {
        const size_t p = base + (size_t)t * HIDc;
        const unsigned kh = *(const unsigned*)(khi + p);
        const unsigned kl = *(const unsigned*)(klo + p);
        const unsigned vh = *(const unsigned*)(vhi + p);
        const unsigned vl = *(const unsigned*)(vlo + p);
        const float kx = elu1(rec2((u16)kh, (u16)kl));
        const float ky = elu1(rec2((u16)(kh >> 16), (u16)(kl >> 16)));
        const float vx = rec2((u16)vh, (u16)vl);
        const float vy = rec2((u16)(vh >> 16), (u16)(vl >> 16));
        skv0 = dec * skv0 + kx * vx;
        skv1 = dec * skv1 + ky * vy;
        sks0 = dec * sks0 + kx;
        sks1 = dec * sks1 + ky;
        u16 h0, l0, h1, l1;
        fsplit(skv0, h0, l0); fsplit(skv1, h1, l1);
        *(unsigned*)(khi + p) = (unsigned)h0 | ((unsigned)h1 << 16);
        *(unsigned*)(klo + p) = (unsigned)l0 | ((unsigned)l1 << 16);
        fsplit(sks0, h0, l0); fsplit(sks1, h1, l1);
        *(unsigned*)(shi + p) = (unsigned)h0 | ((unsigned)h1 << 16);
        *(unsigned*)(slo + p) = (unsigned)l0 | ((unsigned)l1 << 16);
    }
}

// ---------------------------------------------------------------------------
// Chunked scan step 2: carry combine + output.  q pair -> o pair IN PLACE.
// ---------------------------------------------------------------------------
__global__ __launch_bounds__(64) void scan2_k(u16* __restrict__ qhi, u16* __restrict__ qlo,
                                              const u16* __restrict__ skvhi, const u16* __restrict__ skvlo,
                                              const u16* __restrict__ skshi, const u16* __restrict__ skslo,
                                              const float* __restrict__ dp)
{
    const int bid = blockIdx.x;
    const int c   = bid & (NC - 1);
    const int bh  = bid >> 5;
    const int b   = bh >> 3, hh = bh & 7;
    const int lane = threadIdx.x;
    const float dec = sigm(dp[hh]);
    float dCH = dec;
    #pragma unroll
    for (int i = 0; i < 6; i++) dCH *= dCH;      // dec^64
    const size_t rowbase = (size_t)b * Tc * HIDc + hh * HDc + lane * 2;

    float ckv0 = 0.f, ckv1 = 0.f, cks0 = 0.f, cks1 = 0.f;
    for (int j = 0; j < c; j++) {
        const size_t p = rowbase + (size_t)(j * CH + CH - 1) * HIDc;
        const unsigned ah = *(const unsigned*)(skvhi + p);
        const unsigned al = *(const unsigned*)(skvlo + p);
        const unsigned bh2 = *(const unsigned*)(skshi + p);
        const unsigned bl2 = *(const unsigned*)(skslo + p);
        ckv0 = ckv0 * dCH + rec2((u16)ah, (u16)al);
        ckv1 = ckv1 * dCH + rec2((u16)(ah >> 16), (u16)(al >> 16));
        cks0 = cks0 * dCH + rec2((u16)bh2, (u16)bl2);
        cks1 = cks1 * dCH + rec2((u16)(bh2 >> 16), (u16)(bl2 >> 16));
    }

    const size_t cbase = rowbase + (size_t)(c * CH) * HIDc;
    float pw = dec;
    for (int t = 0; t < CH; t++) {
        const size_t p = cbase + (size_t)t * HIDc;
        const unsigned qh = *(const unsigned*)(qhi + p);
        const unsigned ql = *(const unsigned*)(qlo + p);
        const unsigned ah = *(const unsigned*)(skvhi + p);
        const unsigned al = *(const unsigned*)(skvlo + p);
        const unsigned bh2 = *(const unsigned*)(skshi + p);
        const unsigned bl2 = *(const unsigned*)(skslo + p);
        const float qx = elu1(rec2((u16)qh, (u16)ql));
        const float qy = elu1(rec2((u16)(qh >> 16), (u16)(ql >> 16)));
        const float skv0 = rec2((u16)ah, (u16)al) + pw * ckv0;
        const float skv1 = rec2((u16)(ah >> 16), (u16)(al >> 16)) + pw * ckv1;
        const float sks0 = rec2((u16)bh2, (u16)bl2) + pw * cks0;
        const float sks1 = rec2((u16)(bh2 >> 16), (u16)(bl2 >> 16)) + pw * cks1;
        float part = qx * sks0 + qy * sks1;
        #pragma unroll
        for (int o = 32; o > 0; o >>= 1) part += __shfl_xor(part, o);
        const float inv = 1.0f / fmaxf(part, 1e-6f);
        u16 h0, l0, h1, l1;
        fsplit(qx * skv0 * inv, h0, l0);
        fsplit(qy * skv1 * inv, h1, l1);
        *(unsigned*)(qhi + p) = (unsigned)h0 | ((unsigned)h1 << 16);
        *(unsigned*)(qlo + p) = (unsigned)l0 | ((unsigned)l1 << 16);
        pw *= dec;
    }
}

// ---------------------------------------------------------------------------
// fp16-pair MFMA GEMM with global_load_lds staging + XCD-swizzled 1-D grid.
// C = A @ W^T, A exact (hi+lo fp16 pair), W single fp16.
// 128x128 tile, BK=32, 4 waves; wave wv stages k-chunk wv via 6x gld16.
// MODE 0: C = acc  | 1: silu | 2: pair RMW mul | 3: sigmoid-gate(E0,E1)+bias
// MODE 4: sigmoid-gate, A split at kSplit -> A2, C = E0f + g*E1 + (1-g)*E2
// MODE 6: Cout = rec(Cpair) + acc (fp32 out)
// ---------------------------------------------------------------------------
template<int MODE, int PRE>
__global__ __launch_bounds__(256) void gemm_f16_k(
    const u16* __restrict__ Ahi, const u16* __restrict__ Alo,
    const u16* __restrict__ A2hi, const u16* __restrict__ A2lo, int lda,
    const u16* __restrict__ Wh, const float* __restrict__ Wf,
    float* __restrict__ Cout,
    u16* __restrict__ Chi, u16* __restrict__ Clo, int ldc,
    int K, int kSplit, int nx,
    const float* __restrict__ bias,
    const float* __restrict__ E0f,
    const u16* __restrict__ E0hi, const u16* __restrict__ E0lo, int ldE0,
    const u16* __restrict__ E1hi, const u16* __restrict__ E1lo, int ldE1,
    const u16* __restrict__ E2hi, const u16* __restrict__ E2lo, int ldE2)
{
    __shared__ __align__(16) u16 Ah[4][128][8];
    __shared__ __align__(16) u16 Al[4][128][8];
    __shared__ __align__(16) u16 Bs[4][128][8];

    const int tid  = threadIdx.x;
    const int lane = tid & 63;
    const int wv   = tid >> 6;                // wave id == staged k-chunk
    const int wr   = wv >> 1, wc = wv & 1;    // wave 2x2 output grid
    const int lr   = lane & 15, lk = lane >> 4;

    // bijective XCD swizzle (gridDim.x % 8 == 0 for all our launches)
    const int cpx = gridDim.x >> 3;
    int bid = blockIdx.x;
    bid = (bid & 7) * cpx + (bid >> 3);
    const int n0 = (bid % nx) * 128;
    const int m0 = (bid / nx) * 128;

    f32x4 acc[4][4];
    #pragma unroll
    for (int i = 0; i < 4; i++)
        #pragma unroll
        for (int j = 0; j < 4; j++)
            acc[i][j] = (f32x4){0.f, 0.f, 0.f, 0.f};

    for (int k0 = 0; k0 < K; k0 += 32) {
        const u16* ah = Ahi; const u16* al = Alo; int kb = k0;
        if constexpr (MODE == 4) {
            if (k0 >= kSplit) { ah = A2hi; al = A2lo; kb = k0 - kSplit; }
        }
        const size_t a0off = (size_t)(m0 + lane) * lda + kb + wv * 8;
        const size_t a1off = a0off + (size_t)64 * lda;
        F4 wreg[4];
        size_t w0off = 0, w1off = 0;
        if constexpr (PRE) {
            w0off = (size_t)(n0 + lane) * K + k0 + wv * 8;
            w1off = w0off + (size_t)64 * K;
        } else {
            const float* wp0 = Wf + (size_t)(n0 + lane) * K + k0 + wv * 8;
            const float* wp1 = wp0 + (size_t)64 * K;
            wreg[0].v = *(const float4*)(wp0);
            wreg[1].v = *(const float4*)(wp0 + 4);
            wreg[2].v = *(const float4*)(wp1);
            wreg[3].v = *(const float4*)(wp1 + 4);
        }
        __syncthreads();   // previous iteration's LDS reads done
        gld16(ah + a0off, &Ah[wv][0][0]);
        gld16(ah + a1off, &Ah[wv][64][0]);
        gld16(al + a0off, &Al[wv][0][0]);
        gld16(al + a1off, &Al[wv][64][0]);
        if constexpr (PRE) {
            gld16(Wh + w0off, &Bs[wv][0][0]);
            gld16(Wh + w1off, &Bs[wv][64][0]);
        } else {
            H8 W0, W1;
            #pragma unroll
            for (int e = 0; e < 8; e++) {
                W0.h[e] = (f16)wreg[e >> 2].a[e & 3];
                W1.h[e] = (f16)wreg[2 + (e >> 2)].a[e & 3];
            }
            *(int4*)&Bs[wv][lane][0]      = W0.v;
            *(int4*)&Bs[wv][64 + lane][0] = W1.v;
        }
        __syncthreads();   // drains vmcnt (gld_lds) + lgkm (ds_write)
        f16x8 av[4], au[4], bv[4];
        #pragma unroll
        for (int fi = 0; fi < 4; fi++) {
            av[fi] = *(const f16x8*)&Ah[lk][wr * 64 + fi * 16 + lr][0];
            au[fi] = *(const f16x8*)&Al[lk][wr * 64 + fi * 16 + lr][0];
            bv[fi] = *(const f16x8*)&Bs[lk][wc * 64 + fi * 16 + lr][0];
        }
        #pragma unroll
        for (int i = 0; i < 4; i++)
            #pragma unroll
            for (int j = 0; j < 4; j++) {
                acc[i][j] = __builtin_amdgcn_mfma_f32_16x16x32_f16(av[i], bv[j], acc[i][j], 0, 0, 0);
                acc[i][j] = __builtin_amdgcn_mfma_f32_16x16x32_f16(au[i], bv[j], acc[i][j], 0, 0, 0);
            }
    }

    // epilogue: C/D layout col=lane&15, row=(lane>>4)*4+reg
    #pragma unroll
    for (int i = 0; i < 4; i++) {
        #pragma unroll
        for (int j = 0; j < 4; j++) {
            #pragma unroll
            for (int v = 0; v < 4; v++) {
                const size_t r = (size_t)(m0 + wr * 64 + i * 16 + lk * 4 + v);
                const int c = n0 + wc * 64 + j * 16 + lr;
                const size_t idx = r * (size_t)ldc + c;
                float val = acc[i][j][v];
                if constexpr (MODE == 1) {
                    val = silu(val);
                } else if constexpr (MODE == 2) {
                    val = rec2(Chi[idx], Clo[idx]) * val;
                } else if constexpr (MODE == 3) {
                    const float g = sigm(val + bias[c]);
                    const size_t i0 = r * (size_t)ldE0 + c, i1 = r * (size_t)ldE1 + c;
                    val = g * rec2(E0hi[i0], E0lo[i0]) + (1.0f - g) * rec2(E1hi[i1], E1lo[i1]);
                } else if constexpr (MODE == 4) {
                    const float g = sigm(val);
                    const size_t i1 = r * (size_t)ldE1 + c, i2 = r * (size_t)ldE2 + c;
                    val = E0f[r * (size_t)ldE0 + c] + g * rec2(E1hi[i1], E1lo[i1])
                          + (1.0f - g) * rec2(E2hi[i2], E2lo[i2]);
                } else if constexpr (MODE == 6) {
                    Cout[idx] = rec2(Chi[idx], Clo[idx]) + val;
                    continue;
                }
                u16 hh, ll; fsplit(val, hh, ll);
                Chi[idx] = hh; Clo[idx] = ll;
            }
        }
    }
}

template<int MODE>
static inline void launch_gemm(bool pre, int nblocks, int nx, hipStream_t stream,
    const u16* Ahi, const u16* Alo, const u16* A2hi, const u16* A2lo, int lda,
    const u16* Wh, const float* Wf,
    float* Cout, u16* Chi, u16* Clo, int ldc, int K, int kSplit,
    const float* bias, const float* E0f,
    const u16* E0hi, const u16* E0lo, int ldE0,
    const u16* E1hi, const u16* E1lo, int ldE1,
    const u16* E2hi, const u16* E2lo, int ldE2)
{
    if (pre)
        gemm_f16_k<MODE, 1><<<dim3(nblocks), dim3(256), 0, stream>>>(Ahi, Alo, A2hi, A2lo, lda, Wh, Wf,
            Cout, Chi, Clo, ldc, K, kSplit, nx, bias, E0f, E0hi, E0lo, ldE0, E1hi, E1lo, ldE1, E2hi, E2lo, ldE2);
    else
        gemm_f16_k<MODE, 0><<<dim3(nblocks), dim3(256), 0, stream>>>(Ahi, Alo, A2hi, A2lo, lda, Wh, Wf,
            Cout, Chi, Clo, ldc, K, kSplit, nx, bias, E0f, E0hi, E0lo, ldE0, E1hi, E1lo, ldE1, E2hi, E2lo, ldE2);
}

// ---------------------------------------------------------------------------
extern "C" void kernel_launch(void* const* d_in, const int* in_sizes, int n_in,
                              void* d_out, int out_size, void* d_ws, size_t ws_size,
                              hipStream_t stream)
{
    const float* x           = (const float*)d_in[0];
    const float* qkv_w       = (const float*)d_in[1];
    const float* out_proj_w  = (const float*)d_in[2];
    const float* out_gate_w  = (const float*)d_in[3];
    const float* out_gate_b  = (const float*)d_in[4];
    const float* decay_param = (const float*)d_in[5];
    const float* conv_w      = (const float*)d_in[6];
    const float* conv_b      = (const float*)d_in[7];
    const float* pw_w        = (const float*)d_in[8];
    const float* gate_w      = (const float*)d_in[9];
    const float* w1          = (const float*)d_in[10];
    const float* w2          = (const float*)d_in[11];
    const float* w3          = (const float*)d_in[12];
    const float* norm1_w     = (const float*)d_in[13];
    const float* norm2_w     = (const float*)d_in[14];
    float* OUT = (float*)d_out;

    // ---- plane map (each 32MB; pair = hi[S8 u16] + lo[S8 u16]) ----
    float* ws = (float*)d_ws;
    const size_t S8 = (size_t)Mrows * HIDc;   // 8,388,608
    u16* P0h = (u16*)(ws + 0 * S8); u16* P0l = P0h + S8;
    u16* P1h = (u16*)(ws + 1 * S8); u16* P1l = P1h + S8;
    u16* P2h = (u16*)(ws + 2 * S8); u16* P2l = P2h + S8;
    u16* P3h = (u16*)(ws + 3 * S8); u16* P3l = P3h + S8;
    u16* OUTh = (u16*)OUT;          u16* OUTl = OUTh + S8;
    u16* T1h = P1h;                 u16* T1l = P1h + (size_t)Mrows * INTERc;

    constexpr size_t SZ_QKV  = (size_t)3 * HIDc * HIDc;
    constexpr size_t SZ_SQ   = (size_t)HIDc * HIDc;
    constexpr size_t SZ_GATE = (size_t)2 * HIDc * HIDc;
    constexpr size_t SZ_W1   = (size_t)INTERc * HIDc;
    constexpr size_t W_ELEMS = SZ_QKV + 3 * SZ_SQ + SZ_GATE + 3 * SZ_W1;  // 17,039,360
    const bool pre = (ws_size >= 4 * S8 * sizeof(float) + W_ELEMS * sizeof(u16));

    u16* wb   = (u16*)(ws + 4 * S8);
    u16* qkvH = wb;
    u16* pwH  = qkvH + SZ_QKV;
    u16* ogH  = pwH  + SZ_SQ;
    u16* opH  = ogH  + SZ_SQ;
    u16* gaH  = opH  + SZ_SQ;
    u16* w1H  = gaH  + SZ_GATE;
    u16* w2H  = w1H  + SZ_W1;
    u16* w3H  = w2H  + SZ_W1;

    const dim3 blk(256);
    const int nb8  = 8 * (Mrows / 128);    // 512 blocks,  nx=8
    const int nb22 = 22 * (Mrows / 128);   // 1408 blocks, nx=22
    const u16* nu = nullptr;

    if (pre) {
        wcvt_k<<<(int)(SZ_QKV / 8 / 256), blk, 0, stream>>>(qkv_w, qkvH, (int)(SZ_QKV / 8));
        wcvt_k<<<(int)(SZ_SQ  / 8 / 256), blk, 0, stream>>>(pw_w,  pwH,  (int)(SZ_SQ  / 8));
        wcvt_k<<<(int)(SZ_SQ  / 8 / 256), blk, 0, stream>>>(out_gate_w, ogH, (int)(SZ_SQ / 8));
        wcvt_k<<<(int)(SZ_SQ  / 8 / 256), blk, 0, stream>>>(out_proj_w, opH, (int)(SZ_SQ / 8));
        wcvt_k<<<(int)(SZ_GATE/ 8 / 256), blk, 0, stream>>>(gate_w, gaH, (int)(SZ_GATE / 8));
        wcvt_k<<<(int)(SZ_W1  / 8 / 256), blk, 0, stream>>>(w1, w1H, (int)(SZ_W1 / 8));
        wcvt_k<<<(int)(SZ_W1  / 8 / 256), blk, 0, stream>>>(w2, w2H, (int)(SZ_W1 / 8));
        wcvt_k<<<(int)(SZ_W1  / 8 / 256), blk, 0, stream>>>(w3, w3H, (int)(SZ_W1 / 8));
    }

    // 1. h = rmsnorm(x) -> P0 pair
    rmsnorm_k<0><<<Mrows, blk, 0, stream>>>(x, nullptr, nullptr, norm1_w, P0h, P0l);
    // 2. conv(h) -> P1 pair
    conv_k<<<Mrows, blk, 0, stream>>>(P0h, P0l, conv_w, conv_b, P1h, P1l);
    // 3. local = conv @ pw^T -> P2 pair
    launch_gemm<0>(pre, nb8, 8, stream, P1h, P1l, nu, nu, HIDc, pwH, pw_w,
                   nullptr, P2h, P2l, HIDc, HIDc, 0, nullptr, nullptr,
                   nu, nu, 0, nu, nu, 0, nu, nu, 0);
    // 4. q,k,v = h @ qkv^T -> P1, P3, OUT pairs
    launch_gemm<0>(pre, nb8, 8, stream, P0h, P0l, nu, nu, HIDc, qkvH, qkv_w,
                   nullptr, P1h, P1l, HIDc, HIDc, 0, nullptr, nullptr,
                   nu, nu, 0, nu, nu, 0, nu, nu, 0);
    launch_gemm<0>(pre, nb8, 8, stream, P0h, P0l, nu, nu, HIDc, qkvH + SZ_SQ, qkv_w + SZ_SQ,
                   nullptr, P3h, P3l, HIDc, HIDc, 0, nullptr, nullptr,
                   nu, nu, 0, nu, nu, 0, nu, nu, 0);
    launch_gemm<0>(pre, nb8, 8, stream, P0h, P0l, nu, nu, HIDc, qkvH + 2 * SZ_SQ, qkv_w + 2 * SZ_SQ,
                   nullptr, OUTh, OUTl, HIDc, HIDc, 0, nullptr, nullptr,
                   nu, nu, 0, nu, nu, 0, nu, nu, 0);
    // 5a. local scans: skv over k (P3, in place); sks -> P0
    scan1_k<<<Bc * NHc * NC, dim3(64), 0, stream>>>(P3h, P3l, OUTh, OUTl, P0h, P0l, decay_param);
    // 5b. carry + output: o over q (P1, in place)
    scan2_k<<<Bc * NHc * NC, dim3(64), 0, stream>>>(P1h, P1l, P3h, P3l, P0h, P0l, decay_param);
    // 6. out-gate -> P0 pair
    launch_gemm<3>(pre, nb8, 8, stream, P1h, P1l, nu, nu, HIDc, ogH, out_gate_w,
                   nullptr, P0h, P0l, HIDc, HIDc, 0, out_gate_b, nullptr,
                   P1h, P1l, HIDc, OUTh, OUTl, HIDc, nu, nu, 0);
    // 7. attn = o2 @ op^T -> P3 pair
    launch_gemm<0>(pre, nb8, 8, stream, P0h, P0l, nu, nu, HIDc, opH, out_proj_w,
                   nullptr, P3h, P3l, HIDc, HIDc, 0, nullptr, nullptr,
                   nu, nu, 0, nu, nu, 0, nu, nu, 0);
    // 8. gate fusion -> P0 pair (x1)
    launch_gemm<4>(pre, nb8, 8, stream, P2h, P2l, P3h, P3l, HIDc, gaH, gate_w,
                   nullptr, P0h, P0l, HIDc, 2 * HIDc, HIDc, nullptr, x,
                   nu, nu, HIDc, P2h, P2l, HIDc, P3h, P3l, HIDc);
    // 9. h2 = rmsnorm(x1) -> OUT pair (scratch)
    rmsnorm_k<1><<<Mrows, blk, 0, stream>>>(nullptr, P0h, P0l, norm2_w, OUTh, OUTl);
    // 10. t1 = silu(h2 @ w1^T) -> T1 pair
    launch_gemm<1>(pre, nb22, 22, stream, OUTh, OUTl, nu, nu, HIDc, w1H, w1,
                   nullptr, T1h, T1l, INTERc, HIDc, 0, nullptr, nullptr,
                   nu, nu, 0, nu, nu, 0, nu, nu, 0);
    // 11. u = t1 * (h2 @ w2^T)  (pair RMW over T1)
    launch_gemm<2>(pre, nb22, 22, stream, OUTh, OUTl, nu, nu, HIDc, w2H, w2,
                   nullptr, T1h, T1l, INTERc, HIDc, 0, nullptr, nullptr,
                   nu, nu, 0, nu, nu, 0, nu, nu, 0);
    // 12. OUT = x1 + u @ w3^T  (fp32 out to d_out)
    launch_gemm<6>(pre, nb8, 8, stream, T1h, T1l, nu, nu, INTERc, w3H, w3,
                   OUT, P0h, P0l, HIDc, INTERc, 0, nullptr, nullptr,
                   nu, nu, 0, nu, nu, 0, nu, nu, 0);
}